// Round 1
// baseline (1299.936 us; speedup 1.0000x reference)
//
#include <hip/hip_runtime.h>
#include <stdint.h>

// Problem constants (match reference)
#define NN 65536     // total nodes
#define NB 512       // graphs
#define NPG 128      // nodes per graph (contiguous, batch = n/128)
#define NE 262144    // edges
#define EPG 512      // edges per graph (contiguous, intra-graph)
#define HD 256       // hidden
#define BN_EPS 1e-5f

typedef unsigned short u16;
typedef float f32x4 __attribute__((ext_vector_type(4)));
typedef __bf16 bf16x8 __attribute__((ext_vector_type(8)));

__device__ __forceinline__ float b2f(u16 u){
  union { unsigned i; float f; } x; x.i = ((unsigned)u) << 16; return x.f;
}
__device__ __forceinline__ u16 f2b(float f){
  union { float f; unsigned i; } x; x.f = f;
  unsigned r = x.i + 0x7fffu + ((x.i >> 16) & 1u);   // RNE
  return (u16)(r >> 16);
}

// ---------------------------------------------------------------------------
// Pack a fp32 weight [K][cols] into bf16 LDS images, one 128-col block each,
// layout Wt[col][k] with XOR swizzle byte ^= (col&7)<<4 so that the GEMM's
// ds_read_b128 of 8 consecutive k for 16 consecutive cols is ~2-way (free).
// ---------------------------------------------------------------------------
template<int K>
__global__ void __launch_bounds__(256) pack_w(const float* __restrict__ W,
                                              u16* __restrict__ img, int cols)
{
  int idx = blockIdx.x * 256 + threadIdx.x;
  if (idx >= K * cols) return;
  int col = idx / K, k = idx - col * K;
  int cb = col >> 7, cl = col & 127;
  unsigned byte = (unsigned)(cl * (K * 2) + k * 2);
  byte ^= (unsigned)((cl & 7) << 4);
  img[(size_t)cb * 128 * K + (byte >> 1)] = f2b(W[(size_t)k * cols + col]);
}

// ---------------------------------------------------------------------------
// Per-graph GIN aggregation: z = h + segment_sum(h[src], dst).
// Block = (graph g, 64-feature chunk c). h-tile + agg in LDS (68 KB -> 2/CU).
// Wave w serially walks 128 edges, lanes own features -> ds_add_f32 atomics.
// ---------------------------------------------------------------------------
template<int F, bool BF16IN>
__global__ void __launch_bounds__(256) agg_kernel(const void* __restrict__ hin_,
    const int* __restrict__ ei, u16* __restrict__ z)
{
  __shared__ float ht[NPG * 64];
  __shared__ float ag[NPG * 64];
  __shared__ int es[EPG];
  __shared__ int ed[EPG];
  const int g = blockIdx.x, c = blockIdx.y, tid = threadIdx.x;
  for (int i = tid; i < EPG; i += 256){
    es[i] = ei[g * EPG + i] & (NPG - 1);
    ed[i] = ei[NE + g * EPG + i] & (NPG - 1);
  }
  if constexpr (BF16IN){
    const u16* hin = (const u16*)hin_;
    for (int i = tid; i < NPG * 16; i += 256){
      int n = i >> 4, qq = i & 15;
      ushort4 v = *(const ushort4*)(hin + (size_t)(g * NPG + n) * F + c * 64 + qq * 4);
      float* d = &ht[n * 64 + qq * 4];
      d[0] = b2f(v.x); d[1] = b2f(v.y); d[2] = b2f(v.z); d[3] = b2f(v.w);
    }
  } else {
    const float* hin = (const float*)hin_;
    for (int i = tid; i < NPG * 16; i += 256){
      int n = i >> 4, qq = i & 15;
      float4 v = *(const float4*)(hin + (size_t)(g * NPG + n) * F + c * 64 + qq * 4);
      float* d = &ht[n * 64 + qq * 4];
      d[0] = v.x; d[1] = v.y; d[2] = v.z; d[3] = v.w;
    }
  }
  for (int i = tid; i < NPG * 64; i += 256) ag[i] = 0.0f;
  __syncthreads();
  const int f = tid & 63, wg = tid >> 6;
  #pragma unroll 4
  for (int i = 0; i < 128; i++){
    int e = wg * 128 + i;                         // broadcast LDS reads
    atomicAdd(&ag[ed[e] * 64 + f], ht[es[e] * 64 + f]);
  }
  __syncthreads();
  for (int i = tid; i < NPG * 16; i += 256){
    int n = i >> 4, qq = i & 15;
    int o = n * 64 + qq * 4;
    ushort4 ov;
    ov.x = f2b(ht[o + 0] + ag[o + 0]);
    ov.y = f2b(ht[o + 1] + ag[o + 1]);
    ov.z = f2b(ht[o + 2] + ag[o + 2]);
    ov.w = f2b(ht[o + 3] + ag[o + 3]);
    *(ushort4*)(z + (size_t)(g * NPG + n) * F + c * 64 + qq * 4) = ov;
  }
}

// ---------------------------------------------------------------------------
// GEMM: Y[N][256] = act(A[N][K] @ W[K][256] + bias), bf16 in, bf16 out.
// grid (N/128, 2). 4 waves, each 64x64 via 16 x mfma_f32_16x16x32_bf16.
// W staged once into LDS from a pre-swizzled image; A frags direct-from-global.
// STATS: per-column sum/sumsq partials -> pS/pQ[col][rowblock] (deterministic).
// ---------------------------------------------------------------------------
template<int K, int ACT, bool STATS>
__global__ void __launch_bounds__(256) gemm_kernel(
    const u16* __restrict__ A, const u16* __restrict__ Wimg,
    const float* __restrict__ bias, u16* __restrict__ Y,
    float* __restrict__ pS, float* __restrict__ pQ)
{
  __shared__ u16 wlds[128 * K];
  __shared__ float sred[2][2][64];
  __shared__ float qred[2][2][64];
  const int rb = blockIdx.x, cb = blockIdx.y, tid = threadIdx.x;
  const int lane = tid & 63, wid = tid >> 6;
  const int wm = wid & 1, wn = wid >> 1;
  const int l15 = lane & 15, lk = (lane >> 4) * 8;

  { // one-time linear stage of the swizzled W image
    const uint4* src = (const uint4*)(Wimg + (size_t)cb * 128 * K);
    uint4* dst = (uint4*)wlds;
    #pragma unroll
    for (int i = 0; i < (128 * K / 8) / 256; i++) dst[i * 256 + tid] = src[i * 256 + tid];
  }
  __syncthreads();

  f32x4 acc[4][4] = {};
  const u16* Abase = A + (size_t)(rb * 128 + wm * 64 + l15) * K + lk;
  #pragma unroll
  for (int kk = 0; kk < K / 32; kk++){
    bf16x8 af[4], bfr[4];
    #pragma unroll
    for (int mf = 0; mf < 4; mf++)
      af[mf] = *(const bf16x8*)(Abase + (size_t)mf * 16 * K + kk * 32);
    #pragma unroll
    for (int nf = 0; nf < 4; nf++){
      int col = wn * 64 + nf * 16 + l15;
      unsigned byte = (unsigned)(col * (K * 2) + (kk * 32 + lk) * 2);
      byte ^= (unsigned)((col & 7) << 4);
      bfr[nf] = *(const bf16x8*)((const char*)wlds + byte);
    }
    #pragma unroll
    for (int mf = 0; mf < 4; mf++)
      #pragma unroll
      for (int nf = 0; nf < 4; nf++)
        acc[mf][nf] = __builtin_amdgcn_mfma_f32_16x16x32_bf16(af[mf], bfr[nf], acc[mf][nf], 0, 0, 0);
  }

  float s[4] = {0,0,0,0}, q[4] = {0,0,0,0};
  #pragma unroll
  for (int nf = 0; nf < 4; nf++){
    const int colg = cb * 128 + wn * 64 + nf * 16 + l15;
    const float bv = bias[colg];
    #pragma unroll
    for (int mf = 0; mf < 4; mf++){
      const int row = rb * 128 + wm * 64 + mf * 16 + (lane >> 4) * 4;
      #pragma unroll
      for (int j = 0; j < 4; j++){
        float v = acc[mf][nf][j] + bv;
        if (ACT == 0) v = fmaxf(v, 0.0f);
        if (ACT == 1) v = tanhf(v);
        Y[(size_t)(row + j) * HD + colg] = f2b(v);
        if (STATS){ s[nf] += v; q[nf] += v * v; }
      }
    }
  }
  if (STATS){
    #pragma unroll
    for (int nf = 0; nf < 4; nf++){
      float sv = s[nf], qv = q[nf];
      sv += __shfl_xor(sv, 16); sv += __shfl_xor(sv, 32);
      qv += __shfl_xor(qv, 16); qv += __shfl_xor(qv, 32);
      if (lane < 16){ sred[wm][wn][nf * 16 + lane] = sv; qred[wm][wn][nf * 16 + lane] = qv; }
    }
    __syncthreads();
    if (tid < 128){
      int wnt = tid >> 6, ci = tid & 63;
      float sv = sred[0][wnt][ci] + sred[1][wnt][ci];
      float qv = qred[0][wnt][ci] + qred[1][wnt][ci];
      pS[(size_t)(cb * 128 + tid) * NB + rb] = sv;
      pQ[(size_t)(cb * 128 + tid) * NB + rb] = qv;
    }
  }
}

// BN finalize: per-feature mean/var over N -> scale/shift.
__global__ void __launch_bounds__(64) bnfin_kernel(const float* __restrict__ pS,
    const float* __restrict__ pQ, const float* __restrict__ gma,
    const float* __restrict__ bta, float* __restrict__ scale, float* __restrict__ shift)
{
  int c = blockIdx.x, lane = threadIdx.x;
  float s = 0.f, q = 0.f;
  for (int i = lane; i < NB; i += 64){ s += pS[(size_t)c * NB + i]; q += pQ[(size_t)c * NB + i]; }
  for (int m = 32; m; m >>= 1){ s += __shfl_xor(s, m); q += __shfl_xor(q, m); }
  if (lane == 0){
    float mu = s * (1.0f / NN);
    float var = q * (1.0f / NN) - mu * mu;          // biased variance
    float sc = gma[c] * rsqrtf(var + BN_EPS);
    scale[c] = sc;
    shift[c] = bta[c] - mu * sc;
  }
}

// BN apply elementwise: h = y*scale[c] + shift[c], bf16->bf16, 8 elems/thread.
__global__ void __launch_bounds__(256) bnapply_kernel(const u16* __restrict__ y,
    const float* __restrict__ scale, const float* __restrict__ shift, u16* __restrict__ h)
{
  const int idx = blockIdx.x * 256 + threadIdx.x;
  const int c0 = (idx * 8) & 255;
  ushort4 v0 = *(const ushort4*)(y + (size_t)idx * 8);
  ushort4 v1 = *(const ushort4*)(y + (size_t)idx * 8 + 4);
  ushort4 o0, o1;
  o0.x = f2b(b2f(v0.x) * scale[c0 + 0] + shift[c0 + 0]);
  o0.y = f2b(b2f(v0.y) * scale[c0 + 1] + shift[c0 + 1]);
  o0.z = f2b(b2f(v0.z) * scale[c0 + 2] + shift[c0 + 2]);
  o0.w = f2b(b2f(v0.w) * scale[c0 + 3] + shift[c0 + 3]);
  o1.x = f2b(b2f(v1.x) * scale[c0 + 4] + shift[c0 + 4]);
  o1.y = f2b(b2f(v1.y) * scale[c0 + 5] + shift[c0 + 5]);
  o1.z = f2b(b2f(v1.z) * scale[c0 + 6] + shift[c0 + 6]);
  o1.w = f2b(b2f(v1.w) * scale[c0 + 7] + shift[c0 + 7]);
  *(ushort4*)(h + (size_t)idx * 8) = o0;
  *(ushort4*)(h + (size_t)idx * 8 + 4) = o1;
}

// a = softmax(t @ c2w + c2b, axis=1); one wave per node row.
__global__ void __launch_bounds__(256) assign_kernel(const u16* __restrict__ t,
    const float* __restrict__ c2w, const float* __restrict__ c2b, float* __restrict__ a)
{
  const int row = blockIdx.x * 4 + (threadIdx.x >> 6);
  const int lane = threadIdx.x & 63;
  ushort4 tv = *(const ushort4*)(t + (size_t)row * HD + lane * 4);
  float t0 = b2f(tv.x), t1 = b2f(tv.y), t2 = b2f(tv.z), t3 = b2f(tv.w);
  const float4* wp = (const float4*)(c2w + lane * 8);
  float4 w0 = wp[0], w1 = wp[1];
  float s0 = t0 * w0.x + t1 * w0.z + t2 * w1.x + t3 * w1.z;
  float s1 = t0 * w0.y + t1 * w0.w + t2 * w1.y + t3 * w1.w;
  for (int m = 32; m; m >>= 1){ s0 += __shfl_xor(s0, m); s1 += __shfl_xor(s1, m); }
  if (lane == 0){
    s0 += c2b[0]; s1 += c2b[1];
    float mx = fmaxf(s0, s1);
    float e0 = expf(s0 - mx), e1 = expf(s1 - mx);
    float inv = 1.0f / (e0 + e1);
    a[(size_t)row * 2]     = e0 * inv;
    a[(size_t)row * 2 + 1] = e1 * inv;
  }
}

// Per-graph pooling: sub = sum a0*h ; graph = mean h (128 contiguous rows).
__global__ void __launch_bounds__(256) subgraph_kernel(const u16* __restrict__ h,
    const float* __restrict__ a, float* __restrict__ outSub, float* __restrict__ outGraph)
{
  __shared__ float a0s[NPG];
  const int g = blockIdx.x, tid = threadIdx.x;
  if (tid < NPG) a0s[tid] = a[(size_t)(g * NPG + tid) * 2];
  __syncthreads();
  const u16* hg = h + (size_t)g * NPG * HD + tid;
  float sub = 0.f, gs = 0.f;
  for (int n = 0; n < NPG; n++){
    float v = b2f(hg[(size_t)n * HD]);
    sub += a0s[n] * v; gs += v;
  }
  outSub[(size_t)g * HD + tid] = sub;
  outGraph[(size_t)g * HD + tid] = gs * (1.0f / NPG);
}

// Per-graph pooled adjacency 2x2 + connectivity penalty partial.
__global__ void __launch_bounds__(64) adjpen_kernel(const float* __restrict__ a,
    const int* __restrict__ ei, float* __restrict__ pg)
{
  const int g = blockIdx.x, lane = threadIdx.x;
  float m00 = 0.f, m01 = 0.f, m10 = 0.f, m11 = 0.f;
  #pragma unroll
  for (int i = 0; i < EPG / 64; i++){
    int e = g * EPG + lane + i * 64;
    int s = ei[e], d = ei[NE + e];
    float as0 = a[(size_t)s * 2], as1 = a[(size_t)s * 2 + 1];
    float ad0 = a[(size_t)d * 2], ad1 = a[(size_t)d * 2 + 1];
    m00 += as0 * ad0; m01 += as0 * ad1; m10 += as1 * ad0; m11 += as1 * ad1;
  }
  for (int m = 32; m; m >>= 1){
    m00 += __shfl_xor(m00, m); m01 += __shfl_xor(m01, m);
    m10 += __shfl_xor(m10, m); m11 += __shfl_xor(m11, m);
  }
  if (lane == 0){
    float r0 = fmaxf(fabsf(m00) + fabsf(m01), 1e-12f);
    float r1 = fmaxf(fabsf(m10) + fabsf(m11), 1e-12f);
    float d0 = m00 / r0 - 1.0f, d1 = m11 / r1 - 1.0f;
    pg[g] = 0.5f * (d0 * d0 + d1 * d1);
  }
}

__global__ void __launch_bounds__(256) penred_kernel(const float* __restrict__ pg,
                                                     float* __restrict__ outPen)
{
  const int tid = threadIdx.x;
  float s = pg[tid] + pg[tid + 256];
  for (int m = 32; m; m >>= 1) s += __shfl_xor(s, m);
  __shared__ float wsum[4];
  if ((tid & 63) == 0) wsum[tid >> 6] = s;
  __syncthreads();
  if (tid == 0) outPen[0] = (wsum[0] + wsum[1] + wsum[2] + wsum[3]) * (1.0f / NB);
}

// Classifier head: out = log_softmax(relu(sub@l1w+l1b) @ l2w + l2b). fp32.
__global__ void __launch_bounds__(256) head_kernel(const float* __restrict__ sub,
    const float* __restrict__ l1w, const float* __restrict__ l1b,
    const float* __restrict__ l2w, const float* __restrict__ l2b,
    float* __restrict__ outLog)
{
  __shared__ float srow[4][HD];
  const int tid = threadIdx.x, wid = tid >> 6, lane = tid & 63;
  const int row0 = blockIdx.x * 4;
  for (int i = tid; i < 4 * HD; i += 256)
    srow[i >> 8][i & 255] = sub[(size_t)(row0 + (i >> 8)) * HD + (i & 255)];
  __syncthreads();
  const int row = row0 + wid;
  float z0 = 0.f, z1 = 0.f, z2 = 0.f, z3 = 0.f;
  for (int k = 0; k < HD; k++){
    float sv = srow[wid][k];
    const float* wr = l1w + (size_t)k * HD + lane;
    z0 += sv * wr[0]; z1 += sv * wr[64]; z2 += sv * wr[128]; z3 += sv * wr[192];
  }
  float o0 = 0.f, o1 = 0.f;
  float zz;
  zz = fmaxf(z0 + l1b[lane +   0], 0.f); o0 += zz * l2w[(lane +   0) * 2]; o1 += zz * l2w[(lane +   0) * 2 + 1];
  zz = fmaxf(z1 + l1b[lane +  64], 0.f); o0 += zz * l2w[(lane +  64) * 2]; o1 += zz * l2w[(lane +  64) * 2 + 1];
  zz = fmaxf(z2 + l1b[lane + 128], 0.f); o0 += zz * l2w[(lane + 128) * 2]; o1 += zz * l2w[(lane + 128) * 2 + 1];
  zz = fmaxf(z3 + l1b[lane + 192], 0.f); o0 += zz * l2w[(lane + 192) * 2]; o1 += zz * l2w[(lane + 192) * 2 + 1];
  for (int m = 32; m; m >>= 1){ o0 += __shfl_xor(o0, m); o1 += __shfl_xor(o1, m); }
  if (lane == 0){
    o0 += l2b[0]; o1 += l2b[1];
    float mx = fmaxf(o0, o1);
    float lse = mx + logf(expf(o0 - mx) + expf(o1 - mx));
    outLog[(size_t)row * 2]     = o0 - lse;
    outLog[(size_t)row * 2 + 1] = o1 - lse;
  }
}

// ---------------------------------------------------------------------------
extern "C" void kernel_launch(void* const* d_in, const int* in_sizes, int n_in,
                              void* d_out, int out_size, void* d_ws, size_t ws_size,
                              hipStream_t stream)
{
  (void)in_sizes; (void)n_in; (void)out_size; (void)ws_size;
  const float* x    = (const float*)d_in[0];
  const int*   ei   = (const int*)  d_in[1];
  const float* w0_1 = (const float*)d_in[3];
  const float* b0_1 = (const float*)d_in[4];
  const float* w0_2 = (const float*)d_in[5];
  const float* b0_2 = (const float*)d_in[6];
  const float* g0   = (const float*)d_in[7];
  const float* be0  = (const float*)d_in[8];
  const float* wl1  = (const float*)d_in[9];
  const float* bl1  = (const float*)d_in[10];
  const float* wl2  = (const float*)d_in[11];
  const float* bl2  = (const float*)d_in[12];
  const float* gl   = (const float*)d_in[13];
  const float* bel  = (const float*)d_in[14];
  const float* c1w  = (const float*)d_in[15];
  const float* c1b  = (const float*)d_in[16];
  const float* c2w  = (const float*)d_in[17];
  const float* c2b  = (const float*)d_in[18];
  const float* l1w  = (const float*)d_in[19];
  const float* l1b  = (const float*)d_in[20];
  const float* l2w  = (const float*)d_in[21];
  const float* l2b  = (const float*)d_in[22];
  float* out = (float*)d_out;

  char* cur = (char*)d_ws;
  auto carve = [&](size_t bytes) -> void* {
    void* p = (void*)cur; cur += (bytes + 255) & ~(size_t)255; return p;
  };
  u16* B0    = (u16*)carve((size_t)NN * HD * 2);
  u16* B1    = (u16*)carve((size_t)NN * HD * 2);
  u16* B2    = (u16*)carve((size_t)NN * HD * 2);
  u16* iw01  = (u16*)carve((size_t)128 * 256 * 2);
  u16* iw02  = (u16*)carve((size_t)256 * 256 * 2);
  u16* iwl1a = (u16*)carve((size_t)256 * 256 * 2);
  u16* iwl1b = (u16*)carve((size_t)256 * 256 * 2);
  u16* iwl2a = (u16*)carve((size_t)256 * 256 * 2);
  u16* iwl2b = (u16*)carve((size_t)256 * 256 * 2);
  u16* ic1w  = (u16*)carve((size_t)256 * 256 * 2);
  float* aB  = (float*)carve((size_t)NN * 2 * 4);
  float* pS  = (float*)carve((size_t)256 * NB * 4);
  float* pQ  = (float*)carve((size_t)256 * NB * 4);
  float* bsc = (float*)carve(256 * 4);
  float* bsh = (float*)carve(256 * 4);
  float* pg  = (float*)carve(NB * 4);

  dim3 b256(256);
  // pack weights -> swizzled bf16 LDS images (tiny)
  pack_w<128><<<128, b256, 0, stream>>>(w0_1, iw01, 256);
  pack_w<256><<<256, b256, 0, stream>>>(w0_2, iw02, 256);
  pack_w<256><<<256, b256, 0, stream>>>(wl1,             iwl1a, 256);
  pack_w<256><<<256, b256, 0, stream>>>(wl1 + 256 * 256, iwl1b, 256);
  pack_w<256><<<256, b256, 0, stream>>>(wl2,             iwl2a, 256);
  pack_w<256><<<256, b256, 0, stream>>>(wl2 + 256 * 256, iwl2b, 256);
  pack_w<256><<<256, b256, 0, stream>>>(c1w, ic1w, 256);

  // ---- GIN layer 0 (x fp32, K=128) ----
  agg_kernel<128, false><<<dim3(NB, 2), b256, 0, stream>>>((const void*)x, ei, B0);
  gemm_kernel<128, 0, false><<<dim3(NB, 2), b256, 0, stream>>>(B0, iw01, b0_1, B1, nullptr, nullptr);
  gemm_kernel<256, 0, true ><<<dim3(NB, 2), b256, 0, stream>>>(B1, iw02, b0_2, B2, pS, pQ);
  bnfin_kernel<<<256, 64, 0, stream>>>(pS, pQ, g0, be0, bsc, bsh);
  bnapply_kernel<<<NN * HD / 8 / 256, b256, 0, stream>>>(B2, bsc, bsh, B0);
  // ---- GIN layer 1 ----
  agg_kernel<256, true><<<dim3(NB, 4), b256, 0, stream>>>((const void*)B0, ei, B1);
  gemm_kernel<256, 0, false><<<dim3(NB, 2), b256, 0, stream>>>(B1, iwl1a, bl1, B2, nullptr, nullptr);
  gemm_kernel<256, 0, true ><<<dim3(NB, 2), b256, 0, stream>>>(B2, iwl2a, bl2, B1, pS, pQ);
  bnfin_kernel<<<256, 64, 0, stream>>>(pS, pQ, gl, bel, bsc, bsh);
  bnapply_kernel<<<NN * HD / 8 / 256, b256, 0, stream>>>(B1, bsc, bsh, B0);
  // ---- GIN layer 2 ----
  agg_kernel<256, true><<<dim3(NB, 4), b256, 0, stream>>>((const void*)B0, ei, B1);
  gemm_kernel<256, 0, false><<<dim3(NB, 2), b256, 0, stream>>>(B1, iwl1b, bl1 + 256, B2, nullptr, nullptr);
  gemm_kernel<256, 0, true ><<<dim3(NB, 2), b256, 0, stream>>>(B2, iwl2b, bl2 + 256, B1, pS, pQ);
  bnfin_kernel<<<256, 64, 0, stream>>>(pS, pQ, gl + 256, bel + 256, bsc, bsh);
  bnapply_kernel<<<NN * HD / 8 / 256, b256, 0, stream>>>(B1, bsc, bsh, B0);
  // ---- assignment + pooling + penalty + head ----
  gemm_kernel<256, 1, false><<<dim3(NB, 2), b256, 0, stream>>>(B0, ic1w, c1b, B1, nullptr, nullptr);
  assign_kernel<<<NN / 4, b256, 0, stream>>>(B1, c2w, c2b, aB);
  subgraph_kernel<<<NB, b256, 0, stream>>>(B0, aB, out + 1024, out + 1024 + NB * HD);
  adjpen_kernel<<<NB, 64, 0, stream>>>(aB, ei, pg);
  penred_kernel<<<1, b256, 0, stream>>>(pg, out + 1024 + 2 * NB * HD);
  head_kernel<<<NB / 4, b256, 0, stream>>>(out + 1024, l1w, l1b, l2w, l2b, out);
}

// Round 2
// 440.868 us; speedup vs baseline: 2.9486x; 2.9486x over previous
//
#include <hip/hip_runtime.h>
#include <stdint.h>

// Problem constants (match reference)
#define NN 65536     // total nodes
#define NB 512       // graphs
#define NPG 128      // nodes per graph (contiguous, batch = n/128)
#define NE 262144    // edges
#define EPG 512      // edges per graph (contiguous, intra-graph)
#define HD 256       // hidden
#define BN_EPS 1e-5f

typedef unsigned short u16;
typedef float f32x4 __attribute__((ext_vector_type(4)));
typedef __bf16 bf16x8 __attribute__((ext_vector_type(8)));
typedef unsigned short u16x8 __attribute__((ext_vector_type(8)));

__device__ __forceinline__ float b2f(u16 u){
  union { unsigned i; float f; } x; x.i = ((unsigned)u) << 16; return x.f;
}
__device__ __forceinline__ u16 f2b(float f){
  union { float f; unsigned i; } x; x.f = f;
  unsigned r = x.i + 0x7fffu + ((x.i >> 16) & 1u);   // RNE
  return (u16)(r >> 16);
}

// ---------------------------------------------------------------------------
// Pack a fp32 weight [K][cols] into bf16 images, one 128-col block each,
// layout Wt[col][k] with XOR swizzle byte ^= (col&7)<<4 so the GEMM's
// ds_read_b128 of 8 consecutive k for 16 consecutive cols is ~2-way (free).
// ---------------------------------------------------------------------------
template<int K>
__global__ void __launch_bounds__(256) pack_w(const float* __restrict__ W,
                                              u16* __restrict__ img, int cols)
{
  int idx = blockIdx.x * 256 + threadIdx.x;
  if (idx >= K * cols) return;
  int col = idx / K, k = idx - col * K;
  int cb = col >> 7, cl = col & 127;
  unsigned byte = (unsigned)(cl * (K * 2) + k * 2);
  byte ^= (unsigned)((cl & 7) << 4);
  img[(size_t)cb * 128 * K + (byte >> 1)] = f2b(W[(size_t)k * cols + col]);
}

// ---------------------------------------------------------------------------
// GIN aggregation, CSR-gather formulation. Block = (graph g, 128-col half c).
// 1) load edges, count per-dst degrees (int LDS atomics)
// 2) stage h tile [128 nodes][128 cols] as bf16 in LDS
//    MODE 0: fp32 input.  MODE 1: bf16 input.  MODE 2: bf16 input + BN fuse.
// 3) prefix-sum degrees -> CSR rowptr, scatter srcs sorted by dst
// 4) gather: thread owns (node, 16-col chunk), sums self + in-neighbors.
// No float atomics, no serial edge walk.
// ---------------------------------------------------------------------------
template<int F, int MODE>
__global__ void __launch_bounds__(256) agg_kernel(const void* __restrict__ hin_,
    const int* __restrict__ ei, const float* __restrict__ sc,
    const float* __restrict__ sh, u16* __restrict__ z)
{
  __shared__ u16 ht[NPG][128];
  __shared__ int es[EPG];
  __shared__ int ed[EPG];
  __shared__ int srcs[EPG];
  __shared__ int cnt[NPG];
  __shared__ int rp[NPG + 1];
  __shared__ int fill[NPG];
  __shared__ float scs[128], shs[128];
  const int g = blockIdx.x, c = blockIdx.y, tid = threadIdx.x;

  if (tid < NPG) cnt[tid] = 0;
  if (tid == 0) rp[0] = 0;
  if (MODE == 2 && tid >= 128){
    scs[tid - 128] = sc[c * 128 + tid - 128];
    shs[tid - 128] = sh[c * 128 + tid - 128];
  }
  __syncthreads();

  // edges + degree count
  #pragma unroll
  for (int i = 0; i < 2; i++){
    int e = tid + i * 256;
    int s = ei[g * EPG + e] & (NPG - 1);
    int d = ei[NE + g * EPG + e] & (NPG - 1);
    es[e] = s; ed[e] = d;
    atomicAdd(&cnt[d], 1);
  }

  // stage h tile
  if constexpr (MODE == 0){
    const float* hin = (const float*)hin_;
    #pragma unroll
    for (int i = 0; i < 16; i++){
      int u = tid * 4 + i * 1024;
      int n = u >> 7, col = u & 127;
      float4 v = *(const float4*)(hin + (size_t)(g * NPG + n) * F + c * 128 + col);
      u16* d = &ht[n][col];
      d[0] = f2b(v.x); d[1] = f2b(v.y); d[2] = f2b(v.z); d[3] = f2b(v.w);
    }
  } else if constexpr (MODE == 1){
    const u16* hin = (const u16*)hin_;
    #pragma unroll
    for (int i = 0; i < 8; i++){
      int u = tid * 8 + i * 2048;
      int n = u >> 7, col = u & 127;
      *(u16x8*)&ht[n][col] = *(const u16x8*)(hin + (size_t)(g * NPG + n) * F + c * 128 + col);
    }
  } else {
    const u16* hin = (const u16*)hin_;
    #pragma unroll
    for (int i = 0; i < 8; i++){
      int u = tid * 8 + i * 2048;
      int n = u >> 7, col = u & 127;
      u16x8 v = *(const u16x8*)(hin + (size_t)(g * NPG + n) * F + c * 128 + col);
      u16x8 o;
      #pragma unroll
      for (int k = 0; k < 8; k++)
        o[k] = f2b(b2f(v[k]) * scs[col + k] + shs[col + k]);
      *(u16x8*)&ht[n][col] = o;
    }
  }
  __syncthreads();

  // exclusive scan: rp[t+1] = sum cnt[0..t]
  if (tid < NPG) rp[tid + 1] = cnt[tid];
  __syncthreads();
  #pragma unroll
  for (int off = 1; off < NPG; off <<= 1){
    int v = 0;
    if (tid < NPG && tid >= off) v = rp[tid + 1 - off];
    __syncthreads();
    if (tid < NPG && tid >= off) rp[tid + 1] += v;
    __syncthreads();
  }
  if (tid < NPG) fill[tid] = rp[tid];
  __syncthreads();

  // scatter srcs sorted by dst
  #pragma unroll
  for (int i = 0; i < 2; i++){
    int e = tid + i * 256;
    int pos = atomicAdd(&fill[ed[e]], 1);
    srcs[pos] = es[e];
  }
  __syncthreads();

  // gather: thread -> (node n, 16-col chunk fc)
  const int fc = tid & 7, n0 = tid >> 3;
  #pragma unroll
  for (int j = 0; j < 4; j++){
    const int n = n0 + j * 32;
    float acc[16];
    {
      u16x8 a0 = *(const u16x8*)&ht[n][fc * 16];
      u16x8 a1 = *(const u16x8*)&ht[n][fc * 16 + 8];
      #pragma unroll
      for (int k = 0; k < 8; k++){ acc[k] = b2f(a0[k]); acc[8 + k] = b2f(a1[k]); }
    }
    const int e0 = rp[n], e1 = rp[n + 1];
    for (int e = e0; e < e1; e++){
      const u16* hs = &ht[srcs[e]][fc * 16];
      u16x8 a0 = *(const u16x8*)hs;
      u16x8 a1 = *(const u16x8*)(hs + 8);
      #pragma unroll
      for (int k = 0; k < 8; k++){ acc[k] += b2f(a0[k]); acc[8 + k] += b2f(a1[k]); }
    }
    u16* zp = z + (size_t)(g * NPG + n) * F + c * 128 + fc * 16;
    u16x8 o0, o1;
    #pragma unroll
    for (int k = 0; k < 8; k++){ o0[k] = f2b(acc[k]); o1[k] = f2b(acc[8 + k]); }
    *(u16x8*)zp = o0;
    *(u16x8*)(zp + 8) = o1;
  }
}

// ---------------------------------------------------------------------------
// GEMM: Y[N][256] = act(A[N][K] @ W[K][256] + bias), bf16 in, bf16 out.
// grid (N/128, 2). 4 waves, each 64x64 via 16 x mfma_f32_16x16x32_bf16.
// W staged once into LDS from a pre-swizzled image; A frags direct-from-global.
// STATS: per-column sum/sumsq partials -> pS/pQ[col][rowblock] (deterministic).
// ---------------------------------------------------------------------------
template<int K, int ACT, bool STATS>
__global__ void __launch_bounds__(256) gemm_kernel(
    const u16* __restrict__ A, const u16* __restrict__ Wimg,
    const float* __restrict__ bias, u16* __restrict__ Y,
    float* __restrict__ pS, float* __restrict__ pQ)
{
  __shared__ u16 wlds[128 * K];
  __shared__ float sred[2][2][64];
  __shared__ float qred[2][2][64];
  const int rb = blockIdx.x, cb = blockIdx.y, tid = threadIdx.x;
  const int lane = tid & 63, wid = tid >> 6;
  const int wm = wid & 1, wn = wid >> 1;
  const int l15 = lane & 15, lk = (lane >> 4) * 8;

  { // one-time linear stage of the swizzled W image
    const uint4* src = (const uint4*)(Wimg + (size_t)cb * 128 * K);
    uint4* dst = (uint4*)wlds;
    #pragma unroll
    for (int i = 0; i < (128 * K / 8) / 256; i++) dst[i * 256 + tid] = src[i * 256 + tid];
  }
  __syncthreads();

  f32x4 acc[4][4] = {};
  const u16* Abase = A + (size_t)(rb * 128 + wm * 64 + l15) * K + lk;
  #pragma unroll
  for (int kk = 0; kk < K / 32; kk++){
    bf16x8 af[4], bfr[4];
    #pragma unroll
    for (int mf = 0; mf < 4; mf++)
      af[mf] = *(const bf16x8*)(Abase + (size_t)mf * 16 * K + kk * 32);
    #pragma unroll
    for (int nf = 0; nf < 4; nf++){
      int col = wn * 64 + nf * 16 + l15;
      unsigned byte = (unsigned)(col * (K * 2) + (kk * 32 + lk) * 2);
      byte ^= (unsigned)((col & 7) << 4);
      bfr[nf] = *(const bf16x8*)((const char*)wlds + byte);
    }
    #pragma unroll
    for (int mf = 0; mf < 4; mf++)
      #pragma unroll
      for (int nf = 0; nf < 4; nf++)
        acc[mf][nf] = __builtin_amdgcn_mfma_f32_16x16x32_bf16(af[mf], bfr[nf], acc[mf][nf], 0, 0, 0);
  }

  float s[4] = {0,0,0,0}, q[4] = {0,0,0,0};
  #pragma unroll
  for (int nf = 0; nf < 4; nf++){
    const int colg = cb * 128 + wn * 64 + nf * 16 + l15;
    const float bv = bias[colg];
    #pragma unroll
    for (int mf = 0; mf < 4; mf++){
      const int row = rb * 128 + wm * 64 + mf * 16 + (lane >> 4) * 4;
      #pragma unroll
      for (int j = 0; j < 4; j++){
        float v = acc[mf][nf][j] + bv;
        if (ACT == 0) v = fmaxf(v, 0.0f);
        if (ACT == 1) v = tanhf(v);
        Y[(size_t)(row + j) * HD + colg] = f2b(v);
        if (STATS){ s[nf] += v; q[nf] += v * v; }
      }
    }
  }
  if (STATS){
    #pragma unroll
    for (int nf = 0; nf < 4; nf++){
      float sv = s[nf], qv = q[nf];
      sv += __shfl_xor(sv, 16); sv += __shfl_xor(sv, 32);
      qv += __shfl_xor(qv, 16); qv += __shfl_xor(qv, 32);
      if (lane < 16){ sred[wm][wn][nf * 16 + lane] = sv; qred[wm][wn][nf * 16 + lane] = qv; }
    }
    __syncthreads();
    if (tid < 128){
      int wnt = tid >> 6, ci = tid & 63;
      float sv = sred[0][wnt][ci] + sred[1][wnt][ci];
      float qv = qred[0][wnt][ci] + qred[1][wnt][ci];
      pS[(size_t)(cb * 128 + tid) * NB + rb] = sv;
      pQ[(size_t)(cb * 128 + tid) * NB + rb] = qv;
    }
  }
}

// BN finalize: per-feature mean/var over N -> scale/shift.
__global__ void __launch_bounds__(64) bnfin_kernel(const float* __restrict__ pS,
    const float* __restrict__ pQ, const float* __restrict__ gma,
    const float* __restrict__ bta, float* __restrict__ scale, float* __restrict__ shift)
{
  int c = blockIdx.x, lane = threadIdx.x;
  float s = 0.f, q = 0.f;
  for (int i = lane; i < NB; i += 64){ s += pS[(size_t)c * NB + i]; q += pQ[(size_t)c * NB + i]; }
  for (int m = 32; m; m >>= 1){ s += __shfl_xor(s, m); q += __shfl_xor(q, m); }
  if (lane == 0){
    float mu = s * (1.0f / NN);
    float var = q * (1.0f / NN) - mu * mu;          // biased variance
    float sc = gma[c] * rsqrtf(var + BN_EPS);
    scale[c] = sc;
    shift[c] = bta[c] - mu * sc;
  }
}

// BN apply elementwise (final layer only): h = y*scale[c] + shift[c].
__global__ void __launch_bounds__(256) bnapply_kernel(const u16* __restrict__ y,
    const float* __restrict__ scale, const float* __restrict__ shift, u16* __restrict__ h)
{
  const int idx = blockIdx.x * 256 + threadIdx.x;
  const int c0 = (idx * 8) & 255;
  ushort4 v0 = *(const ushort4*)(y + (size_t)idx * 8);
  ushort4 v1 = *(const ushort4*)(y + (size_t)idx * 8 + 4);
  ushort4 o0, o1;
  o0.x = f2b(b2f(v0.x) * scale[c0 + 0] + shift[c0 + 0]);
  o0.y = f2b(b2f(v0.y) * scale[c0 + 1] + shift[c0 + 1]);
  o0.z = f2b(b2f(v0.z) * scale[c0 + 2] + shift[c0 + 2]);
  o0.w = f2b(b2f(v0.w) * scale[c0 + 3] + shift[c0 + 3]);
  o1.x = f2b(b2f(v1.x) * scale[c0 + 4] + shift[c0 + 4]);
  o1.y = f2b(b2f(v1.y) * scale[c0 + 5] + shift[c0 + 5]);
  o1.z = f2b(b2f(v1.z) * scale[c0 + 6] + shift[c0 + 6]);
  o1.w = f2b(b2f(v1.w) * scale[c0 + 7] + shift[c0 + 7]);
  *(ushort4*)(h + (size_t)idx * 8) = o0;
  *(ushort4*)(h + (size_t)idx * 8 + 4) = o1;
}

// a = softmax(t @ c2w + c2b, axis=1); one wave per node row.
__global__ void __launch_bounds__(256) assign_kernel(const u16* __restrict__ t,
    const float* __restrict__ c2w, const float* __restrict__ c2b, float* __restrict__ a)
{
  const int row = blockIdx.x * 4 + (threadIdx.x >> 6);
  const int lane = threadIdx.x & 63;
  ushort4 tv = *(const ushort4*)(t + (size_t)row * HD + lane * 4);
  float t0 = b2f(tv.x), t1 = b2f(tv.y), t2 = b2f(tv.z), t3 = b2f(tv.w);
  const float4* wp = (const float4*)(c2w + lane * 8);
  float4 w0 = wp[0], w1 = wp[1];
  float s0 = t0 * w0.x + t1 * w0.z + t2 * w1.x + t3 * w1.z;
  float s1 = t0 * w0.y + t1 * w0.w + t2 * w1.y + t3 * w1.w;
  for (int m = 32; m; m >>= 1){ s0 += __shfl_xor(s0, m); s1 += __shfl_xor(s1, m); }
  if (lane == 0){
    s0 += c2b[0]; s1 += c2b[1];
    float mx = fmaxf(s0, s1);
    float e0 = expf(s0 - mx), e1 = expf(s1 - mx);
    float inv = 1.0f / (e0 + e1);
    a[(size_t)row * 2]     = e0 * inv;
    a[(size_t)row * 2 + 1] = e1 * inv;
  }
}

// Per-graph pooling: sub = sum a0*h ; graph = mean h (128 contiguous rows).
__global__ void __launch_bounds__(256) subgraph_kernel(const u16* __restrict__ h,
    const float* __restrict__ a, float* __restrict__ outSub, float* __restrict__ outGraph)
{
  __shared__ float a0s[NPG];
  const int g = blockIdx.x, tid = threadIdx.x;
  if (tid < NPG) a0s[tid] = a[(size_t)(g * NPG + tid) * 2];
  __syncthreads();
  const u16* hg = h + (size_t)g * NPG * HD + tid;
  float sub = 0.f, gs = 0.f;
  for (int n = 0; n < NPG; n++){
    float v = b2f(hg[(size_t)n * HD]);
    sub += a0s[n] * v; gs += v;
  }
  outSub[(size_t)g * HD + tid] = sub;
  outGraph[(size_t)g * HD + tid] = gs * (1.0f / NPG);
}

// Per-graph pooled adjacency 2x2 + connectivity penalty partial.
__global__ void __launch_bounds__(64) adjpen_kernel(const float* __restrict__ a,
    const int* __restrict__ ei, float* __restrict__ pg)
{
  const int g = blockIdx.x, lane = threadIdx.x;
  float m00 = 0.f, m01 = 0.f, m10 = 0.f, m11 = 0.f;
  #pragma unroll
  for (int i = 0; i < EPG / 64; i++){
    int e = g * EPG + lane + i * 64;
    int s = ei[e], d = ei[NE + e];
    float as0 = a[(size_t)s * 2], as1 = a[(size_t)s * 2 + 1];
    float ad0 = a[(size_t)d * 2], ad1 = a[(size_t)d * 2 + 1];
    m00 += as0 * ad0; m01 += as0 * ad1; m10 += as1 * ad0; m11 += as1 * ad1;
  }
  for (int m = 32; m; m >>= 1){
    m00 += __shfl_xor(m00, m); m01 += __shfl_xor(m01, m);
    m10 += __shfl_xor(m10, m); m11 += __shfl_xor(m11, m);
  }
  if (lane == 0){
    float r0 = fmaxf(fabsf(m00) + fabsf(m01), 1e-12f);
    float r1 = fmaxf(fabsf(m10) + fabsf(m11), 1e-12f);
    float d0 = m00 / r0 - 1.0f, d1 = m11 / r1 - 1.0f;
    pg[g] = 0.5f * (d0 * d0 + d1 * d1);
  }
}

__global__ void __launch_bounds__(256) penred_kernel(const float* __restrict__ pg,
                                                     float* __restrict__ outPen)
{
  const int tid = threadIdx.x;
  float s = pg[tid] + pg[tid + 256];
  for (int m = 32; m; m >>= 1) s += __shfl_xor(s, m);
  __shared__ float wsum[4];
  if ((tid & 63) == 0) wsum[tid >> 6] = s;
  __syncthreads();
  if (tid == 0) outPen[0] = (wsum[0] + wsum[1] + wsum[2] + wsum[3]) * (1.0f / NB);
}

// Classifier head: out = log_softmax(relu(sub@l1w+l1b) @ l2w + l2b). fp32.
__global__ void __launch_bounds__(256) head_kernel(const float* __restrict__ sub,
    const float* __restrict__ l1w, const float* __restrict__ l1b,
    const float* __restrict__ l2w, const float* __restrict__ l2b,
    float* __restrict__ outLog)
{
  __shared__ float srow[4][HD];
  const int tid = threadIdx.x, wid = tid >> 6, lane = tid & 63;
  const int row0 = blockIdx.x * 4;
  for (int i = tid; i < 4 * HD; i += 256)
    srow[i >> 8][i & 255] = sub[(size_t)(row0 + (i >> 8)) * HD + (i & 255)];
  __syncthreads();
  const int row = row0 + wid;
  float z0 = 0.f, z1 = 0.f, z2 = 0.f, z3 = 0.f;
  for (int k = 0; k < HD; k++){
    float sv = srow[wid][k];
    const float* wr = l1w + (size_t)k * HD + lane;
    z0 += sv * wr[0]; z1 += sv * wr[64]; z2 += sv * wr[128]; z3 += sv * wr[192];
  }
  float o0 = 0.f, o1 = 0.f;
  float zz;
  zz = fmaxf(z0 + l1b[lane +   0], 0.f); o0 += zz * l2w[(lane +   0) * 2]; o1 += zz * l2w[(lane +   0) * 2 + 1];
  zz = fmaxf(z1 + l1b[lane +  64], 0.f); o0 += zz * l2w[(lane +  64) * 2]; o1 += zz * l2w[(lane +  64) * 2 + 1];
  zz = fmaxf(z2 + l1b[lane + 128], 0.f); o0 += zz * l2w[(lane + 128) * 2]; o1 += zz * l2w[(lane + 128) * 2 + 1];
  zz = fmaxf(z3 + l1b[lane + 192], 0.f); o0 += zz * l2w[(lane + 192) * 2]; o1 += zz * l2w[(lane + 192) * 2 + 1];
  for (int m = 32; m; m >>= 1){ o0 += __shfl_xor(o0, m); o1 += __shfl_xor(o1, m); }
  if (lane == 0){
    o0 += l2b[0]; o1 += l2b[1];
    float mx = fmaxf(o0, o1);
    float lse = mx + logf(expf(o0 - mx) + expf(o1 - mx));
    outLog[(size_t)row * 2]     = o0 - lse;
    outLog[(size_t)row * 2 + 1] = o1 - lse;
  }
}

// ---------------------------------------------------------------------------
extern "C" void kernel_launch(void* const* d_in, const int* in_sizes, int n_in,
                              void* d_out, int out_size, void* d_ws, size_t ws_size,
                              hipStream_t stream)
{
  (void)in_sizes; (void)n_in; (void)out_size; (void)ws_size;
  const float* x    = (const float*)d_in[0];
  const int*   ei   = (const int*)  d_in[1];
  const float* w0_1 = (const float*)d_in[3];
  const float* b0_1 = (const float*)d_in[4];
  const float* w0_2 = (const float*)d_in[5];
  const float* b0_2 = (const float*)d_in[6];
  const float* g0   = (const float*)d_in[7];
  const float* be0  = (const float*)d_in[8];
  const float* wl1  = (const float*)d_in[9];
  const float* bl1  = (const float*)d_in[10];
  const float* wl2  = (const float*)d_in[11];
  const float* bl2  = (const float*)d_in[12];
  const float* gl   = (const float*)d_in[13];
  const float* bel  = (const float*)d_in[14];
  const float* c1w  = (const float*)d_in[15];
  const float* c1b  = (const float*)d_in[16];
  const float* c2w  = (const float*)d_in[17];
  const float* c2b  = (const float*)d_in[18];
  const float* l1w  = (const float*)d_in[19];
  const float* l1b  = (const float*)d_in[20];
  const float* l2w  = (const float*)d_in[21];
  const float* l2b  = (const float*)d_in[22];
  float* out = (float*)d_out;

  char* cur = (char*)d_ws;
  auto carve = [&](size_t bytes) -> void* {
    void* p = (void*)cur; cur += (bytes + 255) & ~(size_t)255; return p;
  };
  u16* B0    = (u16*)carve((size_t)NN * HD * 2);
  u16* B1    = (u16*)carve((size_t)NN * HD * 2);
  u16* B2    = (u16*)carve((size_t)NN * HD * 2);
  u16* iw01  = (u16*)carve((size_t)128 * 256 * 2);
  u16* iw02  = (u16*)carve((size_t)256 * 256 * 2);
  u16* iwl1a = (u16*)carve((size_t)256 * 256 * 2);
  u16* iwl1b = (u16*)carve((size_t)256 * 256 * 2);
  u16* iwl2a = (u16*)carve((size_t)256 * 256 * 2);
  u16* iwl2b = (u16*)carve((size_t)256 * 256 * 2);
  u16* ic1w  = (u16*)carve((size_t)256 * 256 * 2);
  float* aB  = (float*)carve((size_t)NN * 2 * 4);
  float* pS  = (float*)carve((size_t)256 * NB * 4);
  float* pQ  = (float*)carve((size_t)256 * NB * 4);
  float* bsc = (float*)carve(256 * 4);
  float* bsh = (float*)carve(256 * 4);
  float* pg  = (float*)carve(NB * 4);

  dim3 b256(256);
  // pack weights -> swizzled bf16 images (tiny)
  pack_w<128><<<128, b256, 0, stream>>>(w0_1, iw01, 256);
  pack_w<256><<<256, b256, 0, stream>>>(w0_2, iw02, 256);
  pack_w<256><<<256, b256, 0, stream>>>(wl1,             iwl1a, 256);
  pack_w<256><<<256, b256, 0, stream>>>(wl1 + 256 * 256, iwl1b, 256);
  pack_w<256><<<256, b256, 0, stream>>>(wl2,             iwl2a, 256);
  pack_w<256><<<256, b256, 0, stream>>>(wl2 + 256 * 256, iwl2b, 256);
  pack_w<256><<<256, b256, 0, stream>>>(c1w, ic1w, 256);

  // ---- GIN layer 0 (x fp32, K=128) ----
  agg_kernel<128, 0><<<dim3(NB, 1), b256, 0, stream>>>((const void*)x, ei, nullptr, nullptr, B0);
  gemm_kernel<128, 0, false><<<dim3(NB, 2), b256, 0, stream>>>(B0, iw01, b0_1, B1, nullptr, nullptr);
  gemm_kernel<256, 0, true ><<<dim3(NB, 2), b256, 0, stream>>>(B1, iw02, b0_2, B2, pS, pQ);
  bnfin_kernel<<<256, 64, 0, stream>>>(pS, pQ, g0, be0, bsc, bsh);
  // ---- GIN layer 1 (BN of layer 0 fused into agg tile load) ----
  agg_kernel<256, 2><<<dim3(NB, 2), b256, 0, stream>>>((const void*)B2, ei, bsc, bsh, B0);
  gemm_kernel<256, 0, false><<<dim3(NB, 2), b256, 0, stream>>>(B0, iwl1a, bl1, B1, nullptr, nullptr);
  gemm_kernel<256, 0, true ><<<dim3(NB, 2), b256, 0, stream>>>(B1, iwl2a, bl2, B2, pS, pQ);
  bnfin_kernel<<<256, 64, 0, stream>>>(pS, pQ, gl, bel, bsc, bsh);
  // ---- GIN layer 2 ----
  agg_kernel<256, 2><<<dim3(NB, 2), b256, 0, stream>>>((const void*)B2, ei, bsc, bsh, B0);
  gemm_kernel<256, 0, false><<<dim3(NB, 2), b256, 0, stream>>>(B0, iwl1b, bl1 + 256, B1, nullptr, nullptr);
  gemm_kernel<256, 0, true ><<<dim3(NB, 2), b256, 0, stream>>>(B1, iwl2b, bl2 + 256, B2, pS, pQ);
  bnfin_kernel<<<256, 64, 0, stream>>>(pS, pQ, gl + 256, bel + 256, bsc, bsh);
  bnapply_kernel<<<NN * HD / 8 / 256, b256, 0, stream>>>(B2, bsc, bsh, B0);
  // ---- assignment + pooling + penalty + head ----
  gemm_kernel<256, 1, false><<<dim3(NB, 2), b256, 0, stream>>>(B0, ic1w, c1b, B1, nullptr, nullptr);
  assign_kernel<<<NN / 4, b256, 0, stream>>>(B1, c2w, c2b, aB);
  subgraph_kernel<<<NB, b256, 0, stream>>>(B0, aB, out + 1024, out + 1024 + NB * HD);
  adjpen_kernel<<<NB, 64, 0, stream>>>(aB, ei, pg);
  penred_kernel<<<1, b256, 0, stream>>>(pg, out + 1024 + 2 * NB * HD);
  head_kernel<<<NB / 4, b256, 0, stream>>>(out + 1024, l1w, l1b, l2w, l2b, out);
}

// Round 5
// 309.405 us; speedup vs baseline: 4.2014x; 1.4249x over previous
//
#include <hip/hip_runtime.h>
#include <stdint.h>

#define NN 65536
#define NB 512
#define NPG 128
#define NE 262144
#define EPG 512
#define HD 256
#define BN_EPS 1e-5f

typedef unsigned short u16;
typedef float f32x4 __attribute__((ext_vector_type(4)));
typedef __bf16 bf16x8 __attribute__((ext_vector_type(8)));
typedef unsigned short u16x8 __attribute__((ext_vector_type(8)));
typedef unsigned short u16x4 __attribute__((ext_vector_type(4)));

__device__ __forceinline__ float b2f(u16 u){
  union { unsigned i; float f; } x; x.i = ((unsigned)u) << 16; return x.f;
}
__device__ __forceinline__ u16 f2b(float f){
  union { float f; unsigned i; } x; x.f = f;
  unsigned r = x.i + 0x7fffu + ((x.i >> 16) & 1u);   // RNE
  return (u16)(r >> 16);
}

// ---------------------------------------------------------------------------
// Pack all weights into bf16 images, layout Wt[col][K] (plain, for global
// B-fragment reads: lane l15 = col, 16B of consecutive k).
// ---------------------------------------------------------------------------
__global__ void __launch_bounds__(256) pack_all(
    const float* __restrict__ w0_1, const float* __restrict__ w0_2,
    const float* __restrict__ wl1, const float* __restrict__ wl2,
    const float* __restrict__ c1w,
    u16* i01, u16* i02, u16* il1a, u16* il1b, u16* il2a, u16* il2b, u16* ic1)
{
  const int seg = blockIdx.y;
  const int idx = blockIdx.x * 256 + threadIdx.x;
  const float* W; u16* img; int K = 256;
  switch (seg){
    case 0: W = w0_1;        img = i01;  K = 128; break;
    case 1: W = w0_2;        img = i02;  break;
    case 2: W = wl1;         img = il1a; break;
    case 3: W = wl1 + 65536; img = il1b; break;
    case 4: W = wl2;         img = il2a; break;
    case 5: W = wl2 + 65536; img = il2b; break;
    default: W = c1w;        img = ic1;  break;
  }
  if (idx >= K * 256) return;
  int col = idx / K, k = idx - col * K;
  img[idx] = f2b(W[(size_t)k * 256 + col]);
}

// ---------------------------------------------------------------------------
// Per-wave GEMM fragment engine: wave computes rows 0..127 x cols
// [c0, c0+32) of A[128][K] @ W[K][256]. A from XOR-swizzled LDS tile,
// B prefetched from global image (L2-resident, read once per block).
// ---------------------------------------------------------------------------
template<int K>
__device__ __forceinline__ void mm_frag(const u16* Alds,
    const u16* __restrict__ wimg, int lane, int c0, f32x4 (&acc)[8][2])
{
  const int l15 = lane & 15, lk = (lane >> 4) * 8;
  bf16x8 bfr[K / 32][2];
  #pragma unroll
  for (int kk = 0; kk < K / 32; kk++)
    #pragma unroll
    for (int nf = 0; nf < 2; nf++)
      bfr[kk][nf] = *(const bf16x8*)(wimg + (size_t)(c0 + nf * 16 + l15) * K + kk * 32 + lk);
  #pragma unroll
  for (int kk = 0; kk < K / 32; kk++){
    bf16x8 af[8];
    #pragma unroll
    for (int mf = 0; mf < 8; mf++){
      int row = mf * 16 + l15;
      unsigned byte = ((unsigned)(row * (K * 2) + (kk * 32 + lk) * 2)) ^ (unsigned)((row & 7) << 4);
      af[mf] = *(const bf16x8*)((const char*)Alds + byte);
    }
    #pragma unroll
    for (int mf = 0; mf < 8; mf++)
      #pragma unroll
      for (int nf = 0; nf < 2; nf++)
        acc[mf][nf] = __builtin_amdgcn_mfma_f32_16x16x32_bf16(af[mf], bfr[kk][nf], acc[mf][nf], 0, 0, 0);
  }
}

// ---------------------------------------------------------------------------
// Fused GIN layer: block = graph. Stage h (+BN) -> CSR agg in LDS ->
// z1 = relu(z@W1+b1) in LDS -> Y = relu(z1@W2+b2) to global + BN stats.
// MODE 0: fp32 input (layer 0), no BN. MODE 1: bf16 input + BN fuse.
// ---------------------------------------------------------------------------
template<int KIN, int MODE>
__global__ void __launch_bounds__(512) layer_kernel(
    const void* __restrict__ hin_, const int* __restrict__ ei,
    const float* __restrict__ sc, const float* __restrict__ sh,
    const u16* __restrict__ w1img, const float* __restrict__ b1,
    const u16* __restrict__ w2img, const float* __restrict__ b2,
    u16* __restrict__ Y, float* __restrict__ pS, float* __restrict__ pQ)
{
  __shared__ u16 ht[NPG * KIN];
  __shared__ u16 z1[NPG * HD];
  __shared__ int es[EPG], ed[EPG], srcs[EPG];
  __shared__ int cnt[NPG], rp[NPG + 1], fill[NPG];
  __shared__ float scs[256], shs[256];
  const int g = blockIdx.x, tid = threadIdx.x;
  const int lane = tid & 63, wid = tid >> 6;

  if (tid < NPG) cnt[tid] = 0;
  if (MODE == 1 && tid < 256){ scs[tid] = sc[tid]; shs[tid] = sh[tid]; }
  __syncthreads();

  { // edges + degree count
    int s = ei[g * EPG + tid] & (NPG - 1);
    int d = ei[NE + g * EPG + tid] & (NPG - 1);
    es[tid] = s; ed[tid] = d;
    atomicAdd(&cnt[d], 1);
  }

  // stage h tile (swizzled bf16)
  if constexpr (MODE == 0){
    const float* hin = (const float*)hin_;
    #pragma unroll
    for (int i = 0; i < 8; i++){
      int idx = tid + i * 512;                 // float4 index
      int row = idx >> 5, c4 = idx & 31;
      float4 v = *(const float4*)(hin + (size_t)(g * NPG + row) * KIN + c4 * 4);
      u16x4 o; o[0] = f2b(v.x); o[1] = f2b(v.y); o[2] = f2b(v.z); o[3] = f2b(v.w);
      unsigned byte = ((unsigned)(row * (KIN * 2) + c4 * 8)) ^ (unsigned)((row & 7) << 4);
      *(u16x4*)((char*)ht + byte) = o;
    }
  } else {
    const u16* hin = (const u16*)hin_;
    #pragma unroll
    for (int i = 0; i < 8; i++){
      int idx = tid + i * 512;                 // u16x8 index
      int row = idx >> 5, c8 = idx & 31;
      u16x8 v = *(const u16x8*)(hin + (size_t)(g * NPG + row) * KIN + c8 * 8);
      u16x8 o;
      #pragma unroll
      for (int k = 0; k < 8; k++) o[k] = f2b(b2f(v[k]) * scs[c8 * 8 + k] + shs[c8 * 8 + k]);
      unsigned byte = ((unsigned)(row * (KIN * 2) + c8 * 16)) ^ (unsigned)((row & 7) << 4);
      *(u16x8*)((char*)ht + byte) = o;
    }
  }
  __syncthreads();

  // wave-0 scan: rp (inclusive->CSR) and fill (exclusive)
  if (tid < 64){
    int a = cnt[tid], b = cnt[tid + 64];
    int ca = a, cb = b;
    #pragma unroll
    for (int off = 1; off < 64; off <<= 1){
      int ta = __shfl_up(a, off), tb = __shfl_up(b, off);
      if (lane >= off){ a += ta; b += tb; }
    }
    int atot = __shfl(a, 63);
    rp[tid + 1] = a;
    rp[tid + 65] = atot + b;
    fill[tid] = a - ca;
    fill[tid + 64] = atot + b - cb;
    if (tid == 0) rp[0] = 0;
  }
  __syncthreads();
  { int pos = atomicAdd(&fill[ed[tid]], 1); srcs[pos] = es[tid]; }
  __syncthreads();

  // gather z = h + sum_{neighbors}
  constexpr int CH = KIN / 16;
  constexpr int RPT = NPG * CH / 512;
  const int fc = tid & (CH - 1), n0 = tid / CH;
  float accv[RPT][16];
  #pragma unroll
  for (int j = 0; j < RPT; j++){
    const int n = n0 + j * (512 / CH);
    unsigned b0 = ((unsigned)(n * (KIN * 2) + fc * 32)) ^ (unsigned)((n & 7) << 4);
    u16x8 a0 = *(const u16x8*)((const char*)ht + b0);
    u16x8 a1 = *(const u16x8*)((const char*)ht + (b0 ^ 16u));
    #pragma unroll
    for (int k = 0; k < 8; k++){ accv[j][k] = b2f(a0[k]); accv[j][8 + k] = b2f(a1[k]); }
    const int e0 = rp[n], e1 = rp[n + 1];
    for (int e = e0; e < e1; e++){
      const int sn = srcs[e];
      unsigned s0 = ((unsigned)(sn * (KIN * 2) + fc * 32)) ^ (unsigned)((sn & 7) << 4);
      u16x8 q0 = *(const u16x8*)((const char*)ht + s0);
      u16x8 q1 = *(const u16x8*)((const char*)ht + (s0 ^ 16u));
      #pragma unroll
      for (int k = 0; k < 8; k++){ accv[j][k] += b2f(q0[k]); accv[j][8 + k] += b2f(q1[k]); }
    }
  }
  __syncthreads();
  #pragma unroll
  for (int j = 0; j < RPT; j++){
    const int n = n0 + j * (512 / CH);
    u16x8 o0, o1;
    #pragma unroll
    for (int k = 0; k < 8; k++){ o0[k] = f2b(accv[j][k]); o1[k] = f2b(accv[j][8 + k]); }
    unsigned b0 = ((unsigned)(n * (KIN * 2) + fc * 32)) ^ (unsigned)((n & 7) << 4);
    *(u16x8*)((char*)ht + b0) = o0;
    *(u16x8*)((char*)ht + (b0 ^ 16u)) = o1;
  }
  __syncthreads();

  // GEMM1: z1 = relu(z @ W1 + b1) -> LDS (swizzled)
  const int c0 = wid * 32;
  const int l15 = lane & 15;
  {
    f32x4 acc1[8][2] = {};
    mm_frag<KIN>(ht, w1img, lane, c0, acc1);
    float bv0 = b1[c0 + l15], bv1 = b1[c0 + 16 + l15];
    #pragma unroll
    for (int mf = 0; mf < 8; mf++)
      #pragma unroll
      for (int nf = 0; nf < 2; nf++){
        float bv = nf ? bv1 : bv0;
        int col = c0 + nf * 16 + l15;
        #pragma unroll
        for (int j = 0; j < 4; j++){
          int row = mf * 16 + (lane >> 4) * 4 + j;
          float v = fmaxf(acc1[mf][nf][j] + bv, 0.f);
          unsigned byte = ((unsigned)(row * 512 + col * 2)) ^ (unsigned)((row & 7) << 4);
          *(u16*)((char*)z1 + byte) = f2b(v);
        }
      }
  }
  __syncthreads();

  // GEMM2: Y = relu(z1 @ W2 + b2) -> global + per-column stats
  {
    f32x4 acc2[8][2] = {};
    mm_frag<HD>(z1, w2img, lane, c0, acc2);
    float bv0 = b2[c0 + l15], bv1 = b2[c0 + 16 + l15];
    float s[2] = {0, 0}, q[2] = {0, 0};
    #pragma unroll
    for (int mf = 0; mf < 8; mf++)
      #pragma unroll
      for (int nf = 0; nf < 2; nf++){
        float bv = nf ? bv1 : bv0;
        int col = c0 + nf * 16 + l15;
        #pragma unroll
        for (int j = 0; j < 4; j++){
          int row = mf * 16 + (lane >> 4) * 4 + j;
          float v = fmaxf(acc2[mf][nf][j] + bv, 0.f);
          Y[(size_t)(g * NPG + row) * HD + col] = f2b(v);
          s[nf] += v; q[nf] += v * v;
        }
      }
    #pragma unroll
    for (int nf = 0; nf < 2; nf++){
      float sv = s[nf], qv = q[nf];
      sv += __shfl_xor(sv, 16); sv += __shfl_xor(sv, 32);
      qv += __shfl_xor(qv, 16); qv += __shfl_xor(qv, 32);
      if (lane < 16){
        int col = c0 + nf * 16 + lane;
        pS[(size_t)col * NB + g] = sv;
        pQ[(size_t)col * NB + g] = qv;
      }
    }
  }
}

// BN finalize: per-feature mean/var over N -> scale/shift.
__global__ void __launch_bounds__(64) bnfin_kernel(const float* __restrict__ pS,
    const float* __restrict__ pQ, const float* __restrict__ gma,
    const float* __restrict__ bta, float* __restrict__ scale, float* __restrict__ shift)
{
  int c = blockIdx.x, lane = threadIdx.x;
  float s = 0.f, q = 0.f;
  for (int i = lane; i < NB; i += 64){ s += pS[(size_t)c * NB + i]; q += pQ[(size_t)c * NB + i]; }
  for (int m = 32; m; m >>= 1){ s += __shfl_xor(s, m); q += __shfl_xor(q, m); }
  if (lane == 0){
    float mu = s * (1.0f / NN);
    float var = q * (1.0f / NN) - mu * mu;
    float scv = gma[c] * rsqrtf(var + BN_EPS);
    scale[c] = scv;
    shift[c] = bta[c] - mu * scv;
  }
}

// ---------------------------------------------------------------------------
// Fused tail per graph: BN(h) -> t=tanh(h@c1w+c1b) -> a=softmax(t@c2w+c2b)
// -> sub/graph pooling, adjacency penalty partial, classifier head.
// ---------------------------------------------------------------------------
__global__ void __launch_bounds__(512) final_kernel(
    const u16* __restrict__ hin, const int* __restrict__ ei,
    const float* __restrict__ sc, const float* __restrict__ sh,
    const u16* __restrict__ c1img, const float* __restrict__ c1b,
    const float* __restrict__ c2w, const float* __restrict__ c2b,
    const float* __restrict__ l1w, const float* __restrict__ l1b,
    const float* __restrict__ l2w, const float* __restrict__ l2b,
    float* __restrict__ outLog, float* __restrict__ outSub,
    float* __restrict__ outGraph, float* __restrict__ pg)
{
  __shared__ u16 ht[NPG * HD];
  __shared__ u16 tt[NPG * HD];
  __shared__ int es[EPG], ed[EPG];
  __shared__ float aL[NPG * 2];
  __shared__ float c2ws[512];
  __shared__ float scs[256], shs[256];
  __shared__ float red2[1024];
  __shared__ float subL[256];
  __shared__ float wred[8][4];
  const int g = blockIdx.x, tid = threadIdx.x;
  const int lane = tid & 63, wid = tid >> 6;

  if (tid < 256){ scs[tid] = sc[tid]; shs[tid] = sh[tid]; }
  c2ws[tid] = c2w[tid];
  es[tid] = ei[g * EPG + tid] & (NPG - 1);
  ed[tid] = ei[NE + g * EPG + tid] & (NPG - 1);
  __syncthreads();

  // stage BN(h) tile (swizzled)
  #pragma unroll
  for (int i = 0; i < 8; i++){
    int idx = tid + i * 512;
    int row = idx >> 5, c8 = idx & 31;
    u16x8 v = *(const u16x8*)(hin + (size_t)(g * NPG + row) * HD + c8 * 8);
    u16x8 o;
    #pragma unroll
    for (int k = 0; k < 8; k++) o[k] = f2b(b2f(v[k]) * scs[c8 * 8 + k] + shs[c8 * 8 + k]);
    unsigned byte = ((unsigned)(row * 512 + c8 * 16)) ^ (unsigned)((row & 7) << 4);
    *(u16x8*)((char*)ht + byte) = o;
  }
  __syncthreads();

  // t = tanh(h @ c1w + c1b) -> tt (plain layout)
  const int c0 = wid * 32;
  const int l15 = lane & 15;
  {
    f32x4 acct[8][2] = {};
    mm_frag<HD>(ht, c1img, lane, c0, acct);
    float bv0 = c1b[c0 + l15], bv1 = c1b[c0 + 16 + l15];
    #pragma unroll
    for (int mf = 0; mf < 8; mf++)
      #pragma unroll
      for (int nf = 0; nf < 2; nf++){
        float bv = nf ? bv1 : bv0;
        int col = c0 + nf * 16 + l15;
        #pragma unroll
        for (int j = 0; j < 4; j++){
          int row = mf * 16 + (lane >> 4) * 4 + j;
          tt[row * HD + col] = f2b(tanhf(acct[mf][nf][j] + bv));
        }
      }
  }
  __syncthreads();

  // a = softmax(t @ c2w + c2b) per row
  {
    const int n = tid >> 2, qd = tid & 3;
    float s0 = 0.f, s1 = 0.f;
    #pragma unroll
    for (int i = 0; i < 8; i++){
      u16x8 v = *(const u16x8*)&tt[n * HD + qd * 64 + i * 8];
      #pragma unroll
      for (int k = 0; k < 8; k++){
        float f = b2f(v[k]); int col = qd * 64 + i * 8 + k;
        s0 += f * c2ws[col * 2]; s1 += f * c2ws[col * 2 + 1];
      }
    }
    s0 += __shfl_xor(s0, 1); s0 += __shfl_xor(s0, 2);
    s1 += __shfl_xor(s1, 1); s1 += __shfl_xor(s1, 2);
    if (qd == 0){
      s0 += c2b[0]; s1 += c2b[1];
      float mx = fmaxf(s0, s1);
      float e0 = expf(s0 - mx), e1 = expf(s1 - mx);
      float inv = 1.f / (e0 + e1);
      aL[n * 2] = e0 * inv; aL[n * 2 + 1] = e1 * inv;
    }
  }
  __syncthreads();

  // adjacency partials (1 edge/thread) + sub/graph partials
  {
    float as0 = aL[es[tid] * 2], as1 = aL[es[tid] * 2 + 1];
    float ad0 = aL[ed[tid] * 2], ad1 = aL[ed[tid] * 2 + 1];
    float m00 = as0 * ad0, m01 = as0 * ad1, m10 = as1 * ad0, m11 = as1 * ad1;
    #pragma unroll
    for (int m = 1; m < 64; m <<= 1){
      m00 += __shfl_xor(m00, m); m01 += __shfl_xor(m01, m);
      m10 += __shfl_xor(m10, m); m11 += __shfl_xor(m11, m);
    }
    if (lane == 0){ wred[wid][0] = m00; wred[wid][1] = m01; wred[wid][2] = m10; wred[wid][3] = m11; }
  }
  {
    const int part = tid >> 8, c = tid & 255;
    float sb = 0.f, gs = 0.f;
    #pragma unroll 8
    for (int i = 0; i < 64; i++){
      int n = part * 64 + i;
      unsigned byte = ((unsigned)(n * 512 + c * 2)) ^ (unsigned)((n & 7) << 4);
      float v = b2f(*(const u16*)((const char*)ht + byte));
      sb += aL[n * 2] * v; gs += v;
    }
    red2[part * 512 + c] = sb;
    red2[part * 512 + 256 + c] = gs;
  }
  __syncthreads();
  if (tid < 256){
    float sb = red2[tid] + red2[512 + tid];
    float gs = red2[256 + tid] + red2[768 + tid];
    subL[tid] = sb;
    outSub[(size_t)g * HD + tid] = sb;
    outGraph[(size_t)g * HD + tid] = gs * (1.f / NPG);
  }
  if (tid == 0){
    float m00 = 0, m01 = 0, m10 = 0, m11 = 0;
    for (int w = 0; w < 8; w++){ m00 += wred[w][0]; m01 += wred[w][1]; m10 += wred[w][2]; m11 += wred[w][3]; }
    float r0 = fmaxf(fabsf(m00) + fabsf(m01), 1e-12f);
    float r1 = fmaxf(fabsf(m10) + fabsf(m11), 1e-12f);
    float d0 = m00 / r0 - 1.f, d1 = m11 / r1 - 1.f;
    pg[g] = 0.5f * (d0 * d0 + d1 * d1);
  }
  __syncthreads();

  // head: z = relu(sub @ l1w + l1b); logits = z @ l2w + l2b; log_softmax
  {
    const int ph = tid >> 8, c = tid & 255;
    float z = 0.f;
    for (int k = ph * 128; k < ph * 128 + 128; k++)
      z += subL[k] * l1w[(size_t)k * HD + c];
    red2[ph * 256 + c] = z;
  }
  __syncthreads();
  if (tid < 256){
    float z = fmaxf(red2[tid] + red2[256 + tid] + l1b[tid], 0.f);
    float o0 = z * l2w[tid * 2], o1 = z * l2w[tid * 2 + 1];
    #pragma unroll
    for (int m = 1; m < 64; m <<= 1){ o0 += __shfl_xor(o0, m); o1 += __shfl_xor(o1, m); }
    if (lane == 0){ wred[wid][0] = o0; wred[wid][1] = o1; }
  }
  __syncthreads();
  if (tid == 0){
    float o0 = wred[0][0] + wred[1][0] + wred[2][0] + wred[3][0] + l2b[0];
    float o1 = wred[0][1] + wred[1][1] + wred[2][1] + wred[3][1] + l2b[1];
    float mx = fmaxf(o0, o1);
    float lse = mx + logf(expf(o0 - mx) + expf(o1 - mx));
    outLog[(size_t)g * 2] = o0 - lse;
    outLog[(size_t)g * 2 + 1] = o1 - lse;
  }
}

__global__ void __launch_bounds__(256) penred_kernel(const float* __restrict__ pg,
                                                     float* __restrict__ outPen)
{
  const int tid = threadIdx.x;
  float s = pg[tid] + pg[tid + 256];
  for (int m = 32; m; m >>= 1) s += __shfl_xor(s, m);
  __shared__ float wsum[4];
  if ((tid & 63) == 0) wsum[tid >> 6] = s;
  __syncthreads();
  if (tid == 0) outPen[0] = (wsum[0] + wsum[1] + wsum[2] + wsum[3]) * (1.0f / NB);
}

// ---------------------------------------------------------------------------
extern "C" void kernel_launch(void* const* d_in, const int* in_sizes, int n_in,
                              void* d_out, int out_size, void* d_ws, size_t ws_size,
                              hipStream_t stream)
{
  (void)in_sizes; (void)n_in; (void)out_size; (void)ws_size;
  const float* x    = (const float*)d_in[0];
  const int*   ei   = (const int*)  d_in[1];
  const float* w0_1 = (const float*)d_in[3];
  const float* b0_1 = (const float*)d_in[4];
  const float* w0_2 = (const float*)d_in[5];
  const float* b0_2 = (const float*)d_in[6];
  const float* g0   = (const float*)d_in[7];
  const float* be0  = (const float*)d_in[8];
  const float* wl1  = (const float*)d_in[9];
  const float* bl1  = (const float*)d_in[10];
  const float* wl2  = (const float*)d_in[11];
  const float* bl2  = (const float*)d_in[12];
  const float* gl   = (const float*)d_in[13];
  const float* bel  = (const float*)d_in[14];
  const float* c1w  = (const float*)d_in[15];
  const float* c1b  = (const float*)d_in[16];
  const float* c2w  = (const float*)d_in[17];
  const float* c2b  = (const float*)d_in[18];
  const float* l1w  = (const float*)d_in[19];
  const float* l1b  = (const float*)d_in[20];
  const float* l2w  = (const float*)d_in[21];
  const float* l2b  = (const float*)d_in[22];
  float* out = (float*)d_out;

  char* cur = (char*)d_ws;
  auto carve = [&](size_t bytes) -> void* {
    void* p = (void*)cur; cur += (bytes + 255) & ~(size_t)255; return p;
  };
  u16* B0    = (u16*)carve((size_t)NN * HD * 2);
  u16* B1    = (u16*)carve((size_t)NN * HD * 2);
  u16* i01   = (u16*)carve((size_t)128 * 256 * 2);
  u16* i02   = (u16*)carve((size_t)256 * 256 * 2);
  u16* il1a  = (u16*)carve((size_t)256 * 256 * 2);
  u16* il1b  = (u16*)carve((size_t)256 * 256 * 2);
  u16* il2a  = (u16*)carve((size_t)256 * 256 * 2);
  u16* il2b  = (u16*)carve((size_t)256 * 256 * 2);
  u16* ic1   = (u16*)carve((size_t)256 * 256 * 2);
  float* pS  = (float*)carve((size_t)256 * NB * 4);
  float* pQ  = (float*)carve((size_t)256 * NB * 4);
  float* bsc = (float*)carve(256 * 4);
  float* bsh = (float*)carve(256 * 4);
  float* pg  = (float*)carve(NB * 4);

  pack_all<<<dim3(256, 7), 256, 0, stream>>>(w0_1, w0_2, wl1, wl2, c1w,
                                             i01, i02, il1a, il1b, il2a, il2b, ic1);

  layer_kernel<128, 0><<<NB, 512, 0, stream>>>((const void*)x, ei, nullptr, nullptr,
                                               i01, b0_1, i02, b0_2, B0, pS, pQ);
  bnfin_kernel<<<256, 64, 0, stream>>>(pS, pQ, g0, be0, bsc, bsh);

  layer_kernel<256, 1><<<NB, 512, 0, stream>>>((const void*)B0, ei, bsc, bsh,
                                               il1a, bl1, il2a, bl2, B1, pS, pQ);
  bnfin_kernel<<<256, 64, 0, stream>>>(pS, pQ, gl, bel, bsc, bsh);

  layer_kernel<256, 1><<<NB, 512, 0, stream>>>((const void*)B1, ei, bsc, bsh,
                                               il1b, bl1 + 256, il2b, bl2 + 256, B0, pS, pQ);
  bnfin_kernel<<<256, 64, 0, stream>>>(pS, pQ, gl + 256, bel + 256, bsc, bsh);

  final_kernel<<<NB, 512, 0, stream>>>(B0, ei, bsc, bsh, ic1, c1b, c2w, c2b,
                                       l1w, l1b, l2w, l2b,
                                       out, out + 1024, out + 1024 + NB * HD, pg);
  penred_kernel<<<1, 256, 0, stream>>>(pg, out + 1024 + 2 * NB * HD);
}

// Round 6
// 288.168 us; speedup vs baseline: 4.5110x; 1.0737x over previous
//
#include <hip/hip_runtime.h>
#include <stdint.h>

#define NN 65536
#define NB 512
#define NPG 128
#define NE 262144
#define EPG 512
#define HD 256
#define BN_EPS 1e-5f

typedef unsigned short u16;
typedef float f32x4 __attribute__((ext_vector_type(4)));
typedef __bf16 bf16x8 __attribute__((ext_vector_type(8)));
typedef unsigned short u16x8 __attribute__((ext_vector_type(8)));
typedef unsigned short u16x4 __attribute__((ext_vector_type(4)));

__device__ __forceinline__ float b2f(u16 u){
  union { unsigned i; float f; } x; x.i = ((unsigned)u) << 16; return x.f;
}
__device__ __forceinline__ u16 f2b(float f){
  union { float f; unsigned i; } x; x.f = f;
  unsigned r = x.i + 0x7fffu + ((x.i >> 16) & 1u);   // RNE
  return (u16)(r >> 16);
}
// fast tanh: 1 - 2/(1+e^{2x}); v_exp + v_rcp, exact at saturation
__device__ __forceinline__ float ftanh(float x){
  float e = __expf(2.0f * x);
  return 1.0f - 2.0f * __builtin_amdgcn_rcpf(e + 1.0f);
}

// ---------------------------------------------------------------------------
// Pack all weights into bf16 images, layout Wt[col][K].
// ---------------------------------------------------------------------------
__global__ void __launch_bounds__(256) pack_all(
    const float* __restrict__ w0_1, const float* __restrict__ w0_2,
    const float* __restrict__ wl1, const float* __restrict__ wl2,
    const float* __restrict__ c1w,
    u16* i01, u16* i02, u16* il1a, u16* il1b, u16* il2a, u16* il2b, u16* ic1)
{
  const int seg = blockIdx.y;
  const int idx = blockIdx.x * 256 + threadIdx.x;
  const float* W; u16* img; int K = 256;
  switch (seg){
    case 0: W = w0_1;        img = i01;  K = 128; break;
    case 1: W = w0_2;        img = i02;  break;
    case 2: W = wl1;         img = il1a; break;
    case 3: W = wl1 + 65536; img = il1b; break;
    case 4: W = wl2;         img = il2a; break;
    case 5: W = wl2 + 65536; img = il2b; break;
    default: W = c1w;        img = ic1;  break;
  }
  if (idx >= K * 256) return;
  int col = idx / K, k = idx - col * K;
  img[idx] = f2b(W[(size_t)k * 256 + col]);
}

// ---------------------------------------------------------------------------
// Per-wave GEMM fragment engine: wave computes rows 0..127 x cols
// [c0, c0+32) of A[128][K] @ W[K][256]. A from XOR-swizzled LDS tile,
// B from global image (L2-resident).
// ---------------------------------------------------------------------------
template<int K>
__device__ __forceinline__ void mm_frag(const u16* Alds,
    const u16* __restrict__ wimg, int lane, int c0, f32x4 (&acc)[8][2])
{
  const int l15 = lane & 15, lk = (lane >> 4) * 8;
  bf16x8 bfr[K / 32][2];
  #pragma unroll
  for (int kk = 0; kk < K / 32; kk++)
    #pragma unroll
    for (int nf = 0; nf < 2; nf++)
      bfr[kk][nf] = *(const bf16x8*)(wimg + (size_t)(c0 + nf * 16 + l15) * K + kk * 32 + lk);
  #pragma unroll
  for (int kk = 0; kk < K / 32; kk++){
    bf16x8 af[8];
    #pragma unroll
    for (int mf = 0; mf < 8; mf++){
      int row = mf * 16 + l15;
      unsigned byte = ((unsigned)(row * (K * 2) + (kk * 32 + lk) * 2)) ^ (unsigned)((row & 7) << 4);
      af[mf] = *(const bf16x8*)((const char*)Alds + byte);
    }
    #pragma unroll
    for (int mf = 0; mf < 8; mf++)
      #pragma unroll
      for (int nf = 0; nf < 2; nf++)
        acc[mf][nf] = __builtin_amdgcn_mfma_f32_16x16x32_bf16(af[mf], bfr[kk][nf], acc[mf][nf], 0, 0, 0);
  }
}

// ---------------------------------------------------------------------------
// Fused GIN layer: block = graph. ht buffer (64KB) is reused for z and z1:
// stage h (+BN) -> CSR agg in place -> GEMM1 acc in regs -> barrier ->
// z1 overwrites ht -> GEMM2 -> global + BN stats. ~71KB LDS -> 2 blocks/CU.
// ---------------------------------------------------------------------------
template<int KIN, int MODE>
__global__ void __launch_bounds__(512) layer_kernel(
    const void* __restrict__ hin_, const int* __restrict__ ei,
    const float* __restrict__ sc, const float* __restrict__ sh,
    const u16* __restrict__ w1img, const float* __restrict__ b1,
    const u16* __restrict__ w2img, const float* __restrict__ b2,
    u16* __restrict__ Y, float* __restrict__ pS, float* __restrict__ pQ)
{
  __shared__ u16 ht[NPG * HD];          // 64KB, holds z then z1
  __shared__ u16 esd[EPG];              // src | dst<<8
  __shared__ u16 srcs[EPG];
  __shared__ int cnt[NPG], rp[NPG + 1], fill[NPG];
  __shared__ float scs[256], shs[256];
  const int g = blockIdx.x, tid = threadIdx.x;
  const int lane = tid & 63, wid = tid >> 6;

  if (tid < NPG) cnt[tid] = 0;
  if (MODE == 1 && tid < 256){ scs[tid] = sc[tid]; shs[tid] = sh[tid]; }
  __syncthreads();

  { // edges + degree count
    int s = ei[g * EPG + tid] & (NPG - 1);
    int d = ei[NE + g * EPG + tid] & (NPG - 1);
    esd[tid] = (u16)(s | (d << 8));
    atomicAdd(&cnt[d], 1);
  }

  // stage h tile (swizzled bf16, row stride KIN*2 bytes)
  if constexpr (MODE == 0){
    const float* hin = (const float*)hin_;
    #pragma unroll
    for (int i = 0; i < 8; i++){
      int idx = tid + i * 512;
      int row = idx >> 5, c4 = idx & 31;
      float4 v = *(const float4*)(hin + (size_t)(g * NPG + row) * KIN + c4 * 4);
      u16x4 o; o[0] = f2b(v.x); o[1] = f2b(v.y); o[2] = f2b(v.z); o[3] = f2b(v.w);
      unsigned byte = ((unsigned)(row * (KIN * 2) + c4 * 8)) ^ (unsigned)((row & 7) << 4);
      *(u16x4*)((char*)ht + byte) = o;
    }
  } else {
    const u16* hin = (const u16*)hin_;
    #pragma unroll
    for (int i = 0; i < 8; i++){
      int idx = tid + i * 512;
      int row = idx >> 5, c8 = idx & 31;
      u16x8 v = *(const u16x8*)(hin + (size_t)(g * NPG + row) * KIN + c8 * 8);
      u16x8 o;
      #pragma unroll
      for (int k = 0; k < 8; k++) o[k] = f2b(b2f(v[k]) * scs[c8 * 8 + k] + shs[c8 * 8 + k]);
      unsigned byte = ((unsigned)(row * (KIN * 2) + c8 * 16)) ^ (unsigned)((row & 7) << 4);
      *(u16x8*)((char*)ht + byte) = o;
    }
  }
  __syncthreads();

  // wave-0 scan: rp (CSR) and fill (exclusive)
  if (tid < 64){
    int a = cnt[tid], b = cnt[tid + 64];
    int ca = a, cb = b;
    #pragma unroll
    for (int off = 1; off < 64; off <<= 1){
      int ta = __shfl_up(a, off), tb = __shfl_up(b, off);
      if (lane >= off){ a += ta; b += tb; }
    }
    int atot = __shfl(a, 63);
    rp[tid + 1] = a;
    rp[tid + 65] = atot + b;
    fill[tid] = a - ca;
    fill[tid + 64] = atot + b - cb;
    if (tid == 0) rp[0] = 0;
  }
  __syncthreads();
  { int v = esd[tid]; int pos = atomicAdd(&fill[v >> 8], 1); srcs[pos] = (u16)(v & 255); }
  __syncthreads();

  // gather z = h + sum_{neighbors} (reads all, barrier, writes back)
  constexpr int CH = KIN / 16;
  constexpr int RPT = NPG * CH / 512;
  const int fc = tid & (CH - 1), n0 = tid / CH;
  float accv[RPT][16];
  #pragma unroll
  for (int j = 0; j < RPT; j++){
    const int n = n0 + j * (512 / CH);
    unsigned b0 = ((unsigned)(n * (KIN * 2) + fc * 32)) ^ (unsigned)((n & 7) << 4);
    u16x8 a0 = *(const u16x8*)((const char*)ht + b0);
    u16x8 a1 = *(const u16x8*)((const char*)ht + (b0 ^ 16u));
    #pragma unroll
    for (int k = 0; k < 8; k++){ accv[j][k] = b2f(a0[k]); accv[j][8 + k] = b2f(a1[k]); }
    const int e0 = rp[n], e1 = rp[n + 1];
    for (int e = e0; e < e1; e++){
      const int sn = srcs[e];
      unsigned s0 = ((unsigned)(sn * (KIN * 2) + fc * 32)) ^ (unsigned)((sn & 7) << 4);
      u16x8 q0 = *(const u16x8*)((const char*)ht + s0);
      u16x8 q1 = *(const u16x8*)((const char*)ht + (s0 ^ 16u));
      #pragma unroll
      for (int k = 0; k < 8; k++){ accv[j][k] += b2f(q0[k]); accv[j][8 + k] += b2f(q1[k]); }
    }
  }
  __syncthreads();
  #pragma unroll
  for (int j = 0; j < RPT; j++){
    const int n = n0 + j * (512 / CH);
    u16x8 o0, o1;
    #pragma unroll
    for (int k = 0; k < 8; k++){ o0[k] = f2b(accv[j][k]); o1[k] = f2b(accv[j][8 + k]); }
    unsigned b0 = ((unsigned)(n * (KIN * 2) + fc * 32)) ^ (unsigned)((n & 7) << 4);
    *(u16x8*)((char*)ht + b0) = o0;
    *(u16x8*)((char*)ht + (b0 ^ 16u)) = o1;
  }
  __syncthreads();

  const int c0 = wid * 32;
  const int l15 = lane & 15;

  // GEMM1 (acc in regs) -> barrier -> z1 overwrites ht (K=256 layout)
  {
    f32x4 acc1[8][2] = {};
    mm_frag<KIN>(ht, w1img, lane, c0, acc1);
    __syncthreads();                       // all reads of z complete
    float bv0 = b1[c0 + l15], bv1 = b1[c0 + 16 + l15];
    #pragma unroll
    for (int mf = 0; mf < 8; mf++)
      #pragma unroll
      for (int nf = 0; nf < 2; nf++){
        float bv = nf ? bv1 : bv0;
        int col = c0 + nf * 16 + l15;
        #pragma unroll
        for (int j = 0; j < 4; j++){
          int row = mf * 16 + (lane >> 4) * 4 + j;
          float v = fmaxf(acc1[mf][nf][j] + bv, 0.f);
          unsigned byte = ((unsigned)(row * 512 + col * 2)) ^ (unsigned)((row & 7) << 4);
          *(u16*)((char*)ht + byte) = f2b(v);
        }
      }
  }
  __syncthreads();

  // GEMM2: Y = relu(z1 @ W2 + b2) -> global + per-column stats
  {
    f32x4 acc2[8][2] = {};
    mm_frag<HD>(ht, w2img, lane, c0, acc2);
    float bv0 = b2[c0 + l15], bv1 = b2[c0 + 16 + l15];
    float s[2] = {0, 0}, q[2] = {0, 0};
    #pragma unroll
    for (int mf = 0; mf < 8; mf++)
      #pragma unroll
      for (int nf = 0; nf < 2; nf++){
        float bv = nf ? bv1 : bv0;
        int col = c0 + nf * 16 + l15;
        #pragma unroll
        for (int j = 0; j < 4; j++){
          int row = mf * 16 + (lane >> 4) * 4 + j;
          float v = fmaxf(acc2[mf][nf][j] + bv, 0.f);
          Y[(size_t)(g * NPG + row) * HD + col] = f2b(v);
          s[nf] += v; q[nf] += v * v;
        }
      }
    #pragma unroll
    for (int nf = 0; nf < 2; nf++){
      float sv = s[nf], qv = q[nf];
      sv += __shfl_xor(sv, 16); sv += __shfl_xor(sv, 32);
      qv += __shfl_xor(qv, 16); qv += __shfl_xor(qv, 32);
      if (lane < 16){
        int col = c0 + nf * 16 + lane;
        pS[(size_t)col * NB + g] = sv;
        pQ[(size_t)col * NB + g] = qv;
      }
    }
  }
}

// BN finalize: per-feature mean/var over N -> scale/shift.
__global__ void __launch_bounds__(64) bnfin_kernel(const float* __restrict__ pS,
    const float* __restrict__ pQ, const float* __restrict__ gma,
    const float* __restrict__ bta, float* __restrict__ scale, float* __restrict__ shift)
{
  int c = blockIdx.x, lane = threadIdx.x;
  float s = 0.f, q = 0.f;
  for (int i = lane; i < NB; i += 64){ s += pS[(size_t)c * NB + i]; q += pQ[(size_t)c * NB + i]; }
  for (int m = 32; m; m >>= 1){ s += __shfl_xor(s, m); q += __shfl_xor(q, m); }
  if (lane == 0){
    float mu = s * (1.0f / NN);
    float var = q * (1.0f / NN) - mu * mu;
    float scv = gma[c] * rsqrtf(var + BN_EPS);
    scale[c] = scv;
    shift[c] = bta[c] - mu * scv;
  }
}

// ---------------------------------------------------------------------------
// Fused tail per graph. tanh+c2-dot in REGISTERS (no tanh tile): per lane
// partial over its 2 cols, shfl_xor over l15, 8KB scratch for cross-wave.
// scratch reused: scs/shs -> softmax partials -> pool partials -> head.
// ~77KB LDS -> 2 blocks/CU.
// ---------------------------------------------------------------------------
__global__ void __launch_bounds__(512) final_kernel(
    const u16* __restrict__ hin, const int* __restrict__ ei,
    const float* __restrict__ sc, const float* __restrict__ sh,
    const u16* __restrict__ c1img, const float* __restrict__ c1b,
    const float* __restrict__ c2w, const float* __restrict__ c2b,
    const float* __restrict__ l1w, const float* __restrict__ l1b,
    const float* __restrict__ l2w, const float* __restrict__ l2b,
    float* __restrict__ outLog, float* __restrict__ outSub,
    float* __restrict__ outGraph, float* __restrict__ outPen)
{
  __shared__ u16 ht[NPG * HD];          // 64KB swizzled BN(h)
  __shared__ u16 esd[EPG];              // 1KB packed edges
  __shared__ float aL[NPG * 2];
  __shared__ float scratch[2048];       // 8KB multi-use
  __shared__ float subL[256];
  __shared__ float wred[8][4];
  const int g = blockIdx.x, tid = threadIdx.x;
  const int lane = tid & 63, wid = tid >> 6;

  if (tid < 256){ scratch[tid] = sc[tid]; scratch[256 + tid] = sh[tid]; }
  {
    int s = ei[g * EPG + tid] & (NPG - 1);
    int d = ei[NE + g * EPG + tid] & (NPG - 1);
    esd[tid] = (u16)(s | (d << 8));
  }
  __syncthreads();

  // stage BN(h) tile (swizzled)
  #pragma unroll
  for (int i = 0; i < 8; i++){
    int idx = tid + i * 512;
    int row = idx >> 5, c8 = idx & 31;
    u16x8 v = *(const u16x8*)(hin + (size_t)(g * NPG + row) * HD + c8 * 8);
    u16x8 o;
    #pragma unroll
    for (int k = 0; k < 8; k++)
      o[k] = f2b(b2f(v[k]) * scratch[c8 * 8 + k] + scratch[256 + c8 * 8 + k]);
    unsigned byte = ((unsigned)(row * 512 + c8 * 16)) ^ (unsigned)((row & 7) << 4);
    *(u16x8*)((char*)ht + byte) = o;
  }
  __syncthreads();

  const int c0 = wid * 32;
  const int l15 = lane & 15;

  // c1 GEMM -> in-register tanh + c2 dot -> scratch[row][wid][2]
  {
    f32x4 acct[8][2] = {};
    mm_frag<HD>(ht, c1img, lane, c0, acct);
    const int col0 = c0 + l15, col1 = c0 + 16 + l15;
    const float bv0 = c1b[col0], bv1 = c1b[col1];
    const float w00 = c2w[col0 * 2], w01 = c2w[col0 * 2 + 1];
    const float w10 = c2w[col1 * 2], w11 = c2w[col1 * 2 + 1];
    #pragma unroll
    for (int mf = 0; mf < 8; mf++)
      #pragma unroll
      for (int j = 0; j < 4; j++){
        float t0 = ftanh(acct[mf][0][j] + bv0);
        float t1 = ftanh(acct[mf][1][j] + bv1);
        float p0 = t0 * w00 + t1 * w10;
        float p1 = t0 * w01 + t1 * w11;
        p0 += __shfl_xor(p0, 1); p0 += __shfl_xor(p0, 2);
        p0 += __shfl_xor(p0, 4); p0 += __shfl_xor(p0, 8);
        p1 += __shfl_xor(p1, 1); p1 += __shfl_xor(p1, 2);
        p1 += __shfl_xor(p1, 4); p1 += __shfl_xor(p1, 8);
        if (l15 == 0){
          int row = mf * 16 + (lane >> 4) * 4 + j;
          scratch[row * 16 + wid * 2]     = p0;
          scratch[row * 16 + wid * 2 + 1] = p1;
        }
      }
  }
  __syncthreads();

  // softmax over 2 logits per row (4 threads/row combine 8 wave partials)
  {
    int row = tid >> 2, part = tid & 3;
    float4 v = *(const float4*)&scratch[row * 16 + part * 4];
    float p0 = v.x + v.z, p1 = v.y + v.w;
    p0 += __shfl_xor(p0, 1); p0 += __shfl_xor(p0, 2);
    p1 += __shfl_xor(p1, 1); p1 += __shfl_xor(p1, 2);
    if (part == 0){
      p0 += c2b[0]; p1 += c2b[1];
      float mx = fmaxf(p0, p1);
      float e0 = expf(p0 - mx), e1 = expf(p1 - mx);
      float inv = 1.f / (e0 + e1);
      aL[row * 2] = e0 * inv; aL[row * 2 + 1] = e1 * inv;
    }
  }
  __syncthreads();

  // adjacency partials (1 edge/thread) + sub/graph pool partials
  {
    int v = esd[tid];
    int sE = v & 255, dE = v >> 8;
    float as0 = aL[sE * 2], as1 = aL[sE * 2 + 1];
    float ad0 = aL[dE * 2], ad1 = aL[dE * 2 + 1];
    float m00 = as0 * ad0, m01 = as0 * ad1, m10 = as1 * ad0, m11 = as1 * ad1;
    #pragma unroll
    for (int m = 1; m < 64; m <<= 1){
      m00 += __shfl_xor(m00, m); m01 += __shfl_xor(m01, m);
      m10 += __shfl_xor(m10, m); m11 += __shfl_xor(m11, m);
    }
    if (lane == 0){ wred[wid][0] = m00; wred[wid][1] = m01; wred[wid][2] = m10; wred[wid][3] = m11; }
  }
  {
    const int part = tid >> 8, c = tid & 255;
    float sb = 0.f, gs = 0.f;
    #pragma unroll 8
    for (int i = 0; i < 64; i++){
      int n = part * 64 + i;
      unsigned byte = ((unsigned)(n * 512 + c * 2)) ^ (unsigned)((n & 7) << 4);
      float v = b2f(*(const u16*)((const char*)ht + byte));
      sb += aL[n * 2] * v; gs += v;
    }
    __syncthreads();                       // softmax partial reads done
    scratch[part * 512 + c] = sb;
    scratch[part * 512 + 256 + c] = gs;
  }
  __syncthreads();
  if (tid < 256){
    float sb = scratch[tid] + scratch[512 + tid];
    float gs = scratch[256 + tid] + scratch[768 + tid];
    subL[tid] = sb;
    outSub[(size_t)g * HD + tid] = sb;
    outGraph[(size_t)g * HD + tid] = gs * (1.f / NPG);
  }
  if (tid == 0){
    float m00 = 0, m01 = 0, m10 = 0, m11 = 0;
    for (int w = 0; w < 8; w++){ m00 += wred[w][0]; m01 += wred[w][1]; m10 += wred[w][2]; m11 += wred[w][3]; }
    float r0 = fmaxf(fabsf(m00) + fabsf(m01), 1e-12f);
    float r1 = fmaxf(fabsf(m10) + fabsf(m11), 1e-12f);
    float d0 = m00 / r0 - 1.f, d1 = m11 / r1 - 1.f;
    atomicAdd(outPen, 0.5f * (d0 * d0 + d1 * d1) * (1.0f / NB));
  }
  __syncthreads();

  // head: z = relu(sub @ l1w + l1b); logits -> log_softmax
  {
    const int ph = tid >> 8, c = tid & 255;
    float z = 0.f;
    for (int k = ph * 128; k < ph * 128 + 128; k++)
      z += subL[k] * l1w[(size_t)k * HD + c];
    scratch[ph * 256 + c] = z;
  }
  __syncthreads();
  if (tid < 256){
    float z = fmaxf(scratch[tid] + scratch[256 + tid] + l1b[tid], 0.f);
    float o0 = z * l2w[tid * 2], o1 = z * l2w[tid * 2 + 1];
    #pragma unroll
    for (int m = 1; m < 64; m <<= 1){ o0 += __shfl_xor(o0, m); o1 += __shfl_xor(o1, m); }
    if (lane == 0){ wred[wid][0] = o0; wred[wid][1] = o1; }
  }
  __syncthreads();
  if (tid == 0){
    float o0 = wred[0][0] + wred[1][0] + wred[2][0] + wred[3][0] + l2b[0];
    float o1 = wred[0][1] + wred[1][1] + wred[2][1] + wred[3][1] + l2b[1];
    float mx = fmaxf(o0, o1);
    float lse = mx + logf(expf(o0 - mx) + expf(o1 - mx));
    outLog[(size_t)g * 2] = o0 - lse;
    outLog[(size_t)g * 2 + 1] = o1 - lse;
  }
}

// ---------------------------------------------------------------------------
extern "C" void kernel_launch(void* const* d_in, const int* in_sizes, int n_in,
                              void* d_out, int out_size, void* d_ws, size_t ws_size,
                              hipStream_t stream)
{
  (void)in_sizes; (void)n_in; (void)out_size; (void)ws_size;
  const float* x    = (const float*)d_in[0];
  const int*   ei   = (const int*)  d_in[1];
  const float* w0_1 = (const float*)d_in[3];
  const float* b0_1 = (const float*)d_in[4];
  const float* w0_2 = (const float*)d_in[5];
  const float* b0_2 = (const float*)d_in[6];
  const float* g0   = (const float*)d_in[7];
  const float* be0  = (const float*)d_in[8];
  const float* wl1  = (const float*)d_in[9];
  const float* bl1  = (const float*)d_in[10];
  const float* wl2  = (const float*)d_in[11];
  const float* bl2  = (const float*)d_in[12];
  const float* gl   = (const float*)d_in[13];
  const float* bel  = (const float*)d_in[14];
  const float* c1w  = (const float*)d_in[15];
  const float* c1b  = (const float*)d_in[16];
  const float* c2w  = (const float*)d_in[17];
  const float* c2b  = (const float*)d_in[18];
  const float* l1w  = (const float*)d_in[19];
  const float* l1b  = (const float*)d_in[20];
  const float* l2w  = (const float*)d_in[21];
  const float* l2b  = (const float*)d_in[22];
  float* out = (float*)d_out;

  char* cur = (char*)d_ws;
  auto carve = [&](size_t bytes) -> void* {
    void* p = (void*)cur; cur += (bytes + 255) & ~(size_t)255; return p;
  };
  u16* B0    = (u16*)carve((size_t)NN * HD * 2);
  u16* B1    = (u16*)carve((size_t)NN * HD * 2);
  u16* i01   = (u16*)carve((size_t)128 * 256 * 2);
  u16* i02   = (u16*)carve((size_t)256 * 256 * 2);
  u16* il1a  = (u16*)carve((size_t)256 * 256 * 2);
  u16* il1b  = (u16*)carve((size_t)256 * 256 * 2);
  u16* il2a  = (u16*)carve((size_t)256 * 256 * 2);
  u16* il2b  = (u16*)carve((size_t)256 * 256 * 2);
  u16* ic1   = (u16*)carve((size_t)256 * 256 * 2);
  float* pS  = (float*)carve((size_t)256 * NB * 4);
  float* pQ  = (float*)carve((size_t)256 * NB * 4);
  float* bsc = (float*)carve(256 * 4);
  float* bsh = (float*)carve(256 * 4);

  float* outPen = out + 1024 + 2 * NB * HD;

  pack_all<<<dim3(256, 7), 256, 0, stream>>>(w0_1, w0_2, wl1, wl2, c1w,
                                             i01, i02, il1a, il1b, il2a, il2b, ic1);
  hipMemsetAsync((void*)outPen, 0, 4, stream);

  layer_kernel<128, 0><<<NB, 512, 0, stream>>>((const void*)x, ei, nullptr, nullptr,
                                               i01, b0_1, i02, b0_2, B0, pS, pQ);
  bnfin_kernel<<<256, 64, 0, stream>>>(pS, pQ, g0, be0, bsc, bsh);

  layer_kernel<256, 1><<<NB, 512, 0, stream>>>((const void*)B0, ei, bsc, bsh,
                                               il1a, bl1, il2a, bl2, B1, pS, pQ);
  bnfin_kernel<<<256, 64, 0, stream>>>(pS, pQ, gl, bel, bsc, bsh);

  layer_kernel<256, 1><<<NB, 512, 0, stream>>>((const void*)B1, ei, bsc, bsh,
                                               il1b, bl1 + 256, il2b, bl2 + 256, B0, pS, pQ);
  bnfin_kernel<<<256, 64, 0, stream>>>(pS, pQ, gl + 256, bel + 256, bsc, bsh);

  final_kernel<<<NB, 512, 0, stream>>>(B0, ei, bsc, bsh, ic1, c1b, c2w, c2b,
                                       l1w, l1b, l2w, l2b,
                                       out, out + 1024, out + 1024 + NB * HD, outPen);
}